// Round 6
// baseline (535.978 us; speedup 1.0000x reference)
//
#include <hip/hip_runtime.h>
#include <stdint.h>

// MAHA decoder block, MI355X/gfx950. Round 11: launch consolidation —
// R3 GEMM restored (best measured; grid dispatch, counted vmcnt);
// mega-launch {wqkv GEMM + Wo/Wg/Wu/Wdn transposes + pad + rmsA4};
// rmsA4 computes both pool levels in-register (pool_k deleted);
// gram last-block computes head inline (head_k deleted); down-proj MT=2 (512 blocks).
// B=2, N=2048, D=1024, H=16(dh=64), L=3, R=2, HID=2734(->2816), fp32 I/O.

#define B_   2
#define N_   2048
#define D_   1024
#define H_   16
#define DH_  64
#define HID_ 2734
#define HIDP 2816
#define CNT  (B_*N_*D_)   // 4194304
#define LOG2E 1.4426950408889634f

typedef unsigned short u16;
typedef __attribute__((ext_vector_type(8))) short short8;
typedef __attribute__((ext_vector_type(4))) float f32x4;
typedef __attribute__((ext_vector_type(4))) uint16_t u16x4;

__device__ __forceinline__ u16 f2bf(float f) {
  uint32_t u = __builtin_bit_cast(uint32_t, f);
  u += 0x7fffu + ((u >> 16) & 1u);          // RNE
  return (u16)(u >> 16);
}
__device__ __forceinline__ float bf2f(u16 h) {
  uint32_t u = ((uint32_t)h) << 16;
  return __builtin_bit_cast(float, u);
}
__device__ __forceinline__ uint32_t pkbf(float a, float b) {
  return (uint32_t)f2bf(a) | ((uint32_t)f2bf(b) << 16);
}
__device__ __forceinline__ void gload_lds16(const void* g, void* l) {
  __builtin_amdgcn_global_load_lds(
      (const __attribute__((address_space(1))) uint32_t*)g,
      (__attribute__((address_space(3))) uint32_t*)l, 16, 0, 0);
}

// ============ weight prep 1: QKV transposes + Wdec convert + SC zero ====
// blocks: [0,9216) QKV weight transposes | [9216,12288) Wdec plain convert
__global__ __launch_bounds__(256) void wprep1_k(const float* __restrict__ Wdec, const float* __restrict__ Wq,
                                                const float* __restrict__ Wk, const float* __restrict__ Wv,
                                                u16* __restrict__ A_wp, u16* __restrict__ WdecB,
                                                float* __restrict__ SCb) {
  const int bid = blockIdx.x;
  if (bid >= 9216) {
    if (bid == 9216 && threadIdx.x < 64) SCb[threadIdx.x] = 0.f;
    int i = (bid - 9216)*1024 + threadIdx.x*4;
    float4 v = *(const float4*)(Wdec + i);
    u16x4 o; o[0]=f2bf(v.x); o[1]=f2bf(v.y); o[2]=f2bf(v.z); o[3]=f2bf(v.w);
    *(u16x4*)(WdecB + i) = o;
    return;
  }
  int j = bid >> 10, t = bid & 1023;
  int bx = t & 31, by = t >> 5;
  int l = j / 3, which = j - l*3;
  const float* src = which==0 ? Wq + (size_t)l*1048576 : which==1 ? Wk + (size_t)l*1048576 : Wv;
  u16* dst = A_wp + (size_t)(l*3072 + which*1024)*1024;
  const float scale = (which==0) ? 0.125f*LOG2E : 1.f;
  __shared__ float tt[32][33];
  const int tx = threadIdx.x & 31, ty = threadIdx.x >> 5;
  const int nb = bx*32, kb = by*32;
  #pragma unroll
  for (int i = 0; i < 4; i++)
    tt[ty + i*8][tx] = src[(size_t)(kb + ty + i*8) * 1024 + nb + tx] * scale;
  __syncthreads();
  #pragma unroll
  for (int i = 0; i < 4; i++)
    dst[(size_t)(nb + ty + i*8) * 1024 + kb + tx] = f2bf(tt[tx][ty + i*8]);
}

// ============ MEGA launch: wqkv GEMM + remaining weight preps + rmsA4 ============
// [0,576):      wqkv GEMM tiles (M=9216/128=72 x N=1024/128=8, x-fastest)
// [576,1600):   Wo transpose        [1600,4416): Wg (gate-ilv)
// [4416,7232):  Wu (up-ilv)         [7232,10048): Wdn
// [10048,10212): BTgu pad zero      [10212,11236): rmsA4 (4 rows + both pools)
__global__ __launch_bounds__(256, 2) void mega_k(const u16* __restrict__ A_wp, const u16* __restrict__ WdecB,
                                                 u16* __restrict__ Wqkv,
                                                 const float* __restrict__ Wo, const float* __restrict__ Wg,
                                                 const float* __restrict__ Wu, const float* __restrict__ Wdn,
                                                 u16* __restrict__ WoT, u16* __restrict__ BTgu,
                                                 u16* __restrict__ WdnT,
                                                 const float* __restrict__ x, const float* __restrict__ nw1,
                                                 u16* __restrict__ xn, u16* __restrict__ xp1,
                                                 u16* __restrict__ xp2) {
  const int bid = blockIdx.x;
  const int tid = threadIdx.x;
  if (bid < 576) {
    // ---- wqkv GEMM tile: F_l^T = [Wq|Wk|Wv]_l^T x Wdec_l^T, 128x128, K=1024 ----
    __shared__ __align__(16) u16 As[2][128*64];
    __shared__ __align__(16) u16 Bs[2][128*64];
    const int lane = tid & 63, wid = tid >> 6;
    const int quad = lane >> 4, c16 = lane & 15;
    const int bx = bid & 7, by = bid >> 3;
    const int m0 = by * 128, n0 = bx * 128;
    const int wm = wid >> 1, wn = wid & 1;
    const int level = (by >= 48) ? 2 : ((by >= 24) ? 1 : 0);
    const u16* BT = WdecB + (size_t)level * 1048576;
    const u16* A = A_wp;

    f32x4 acc[4][4];
    #pragma unroll
    for (int i = 0; i < 4; i++)
      #pragma unroll
      for (int j = 0; j < 4; j++) acc[i][j] = f32x4{0.f,0.f,0.f,0.f};

    const int srow = lane >> 3, schunk = lane & 7;
    auto stage = [&](int k0, int p) {
      #pragma unroll
      for (int t = 0; t < 4; t++) {
        int idx = wid*4 + t;
        int row = idx*8 + srow;
        int g = (schunk ^ (row & 7)) * 8;
        gload_lds16(A + (size_t)(m0+row)*1024 + k0 + g, &As[p][idx*512]);
      }
      #pragma unroll
      for (int t = 0; t < 4; t++) {
        int idx = wid*4 + t;
        int row = idx*8 + srow;
        int g = (schunk ^ (row & 7)) * 8;
        gload_lds16(BT + (size_t)(n0+row)*1024 + k0 + g, &Bs[p][idx*512]);
      }
    };
    stage(0, 0);
    for (int ki = 0; ki < 16; ki++) {
      const int p = ki & 1;
      if (ki + 1 < 16) {
        stage((ki + 1) << 6, p ^ 1);
        asm volatile("s_waitcnt vmcnt(8)" ::: "memory");
      } else {
        asm volatile("s_waitcnt vmcnt(0)" ::: "memory");
      }
      __builtin_amdgcn_s_barrier();
      __builtin_amdgcn_sched_barrier(0);
      __builtin_amdgcn_s_setprio(1);
      #pragma unroll
      for (int kh = 0; kh < 2; kh++) {
        short8 af[4], bfr[4];
        #pragma unroll
        for (int mt = 0; mt < 4; mt++) {
          int ar = wm*64 + mt*16 + c16;
          int ck = (kh*4 + quad) ^ (ar & 7);
          af[mt] = *(const short8*)(&As[p][ar*64 + ck*8]);
        }
        #pragma unroll
        for (int nt = 0; nt < 4; nt++) {
          int br = wn*64 + nt*16 + c16;
          int ck = (kh*4 + quad) ^ (br & 7);
          bfr[nt] = *(const short8*)(&Bs[p][br*64 + ck*8]);
        }
        #pragma unroll
        for (int mt = 0; mt < 4; mt++)
          #pragma unroll
          for (int nt = 0; nt < 4; nt++)
            acc[mt][nt] = __builtin_amdgcn_mfma_f32_16x16x32_bf16(af[mt], bfr[nt], acc[mt][nt], 0, 0, 0);
      }
      __builtin_amdgcn_s_setprio(0);
      __builtin_amdgcn_sched_barrier(0);
      __builtin_amdgcn_s_barrier();
    }
    #pragma unroll
    for (int mt = 0; mt < 4; mt++)
      #pragma unroll
      for (int nt = 0; nt < 4; nt++)
        #pragma unroll
        for (int r = 0; r < 4; r++) {
          int row = m0 + wm*64 + mt*16 + quad*4 + r;
          int col = n0 + wn*64 + nt*16 + c16;
          Wqkv[(size_t)row * 1024 + col] = f2bf(acc[mt][nt][r]);
        }
    return;
  }
  const int t2v = bid - 576;
  if (t2v < 9472) {
    // ---- weight transposes: Wo / Wg(ilv) / Wu(ilv) / Wdn ----
    const float* src; u16* dst; int K, N, KP, imode, bx, by;
    if (t2v < 1024)      { src = Wo;  dst = WoT;  K=1024; N=1024; KP=1024; imode=0; bx=t2v&31; by=t2v>>5; }
    else if (t2v < 3840) { int t = t2v-1024; src = Wg; dst = BTgu; K=1024; N=HID_; KP=1024; imode=1; bx=t%88; by=t/88; }
    else if (t2v < 6656) { int t = t2v-3840; src = Wu; dst = BTgu; K=1024; N=HID_; KP=1024; imode=2; bx=t%88; by=t/88; }
    else                 { int t = t2v-6656; src = Wdn; dst = WdnT; K=HID_; N=1024; KP=HIDP; imode=0; bx=t&31; by=t>>5; }
    __shared__ float tt[32][33];
    const int tx = tid & 31, ty = tid >> 5;
    const int nb = bx*32, kb = by*32;
    #pragma unroll
    for (int i = 0; i < 4; i++) {
      int k = kb + ty + i*8, n = nb + tx;
      tt[ty + i*8][tx] = (k < K && n < N) ? src[(size_t)k * N + n] : 0.f;
    }
    __syncthreads();
    #pragma unroll
    for (int i = 0; i < 4; i++) {
      int n = nb + ty + i*8, k = kb + tx;
      int r;
      if (imode == 0) r = n;
      else if (imode == 1) r = ((n>>4)<<5) + (n&15);
      else r = ((n>>4)<<5) + 16 + (n&15);
      dst[(size_t)r * KP + k] = f2bf(tt[tx][ty + i*8]);
    }
    return;
  }
  if (t2v < 9636) {
    // ---- BTgu pad-row zero-fill (rows 5454,5455,5470..5631) ----
    int b0 = t2v - 9472;
    int row = (b0 < 2) ? (5454 + b0) : (5470 + (b0 - 2));
    u16x4 zz; zz[0]=0; zz[1]=0; zz[2]=0; zz[3]=0;
    *(u16x4*)(BTgu + (size_t)row*1024 + tid*4) = zz;
    return;
  }
  // ---- rmsA4: 4 rows per block + pool1 (2 rows) + pool2 (1 row), all in-register ----
  {
    const int j = t2v - 9636;
    const float* xr = x + (size_t)(4*j) * D_;
    float a0[4], a1[4], a2[4], a3[4], wv[4];
    float s0=0.f, s1=0.f, s2=0.f, s3=0.f;
    #pragma unroll
    for (int i = 0; i < 4; i++) {
      int c = tid + i*256;
      wv[i] = nw1[c];
      a0[i] = xr[c]; a1[i] = xr[D_+c]; a2[i] = xr[2*D_+c]; a3[i] = xr[3*D_+c];
      s0 += a0[i]*a0[i]; s1 += a1[i]*a1[i]; s2 += a2[i]*a2[i]; s3 += a3[i]*a3[i];
    }
    #pragma unroll
    for (int o = 1; o < 64; o <<= 1) {
      s0 += __shfl_xor(s0, o); s1 += __shfl_xor(s1, o);
      s2 += __shfl_xor(s2, o); s3 += __shfl_xor(s3, o);
    }
    __shared__ float rr[4][4];
    if ((tid & 63) == 0) { int w = tid >> 6; rr[w][0]=s0; rr[w][1]=s1; rr[w][2]=s2; rr[w][3]=s3; }
    __syncthreads();
    float m0v = rr[0][0]+rr[1][0]+rr[2][0]+rr[3][0];
    float m1v = rr[0][1]+rr[1][1]+rr[2][1]+rr[3][1];
    float m2v = rr[0][2]+rr[1][2]+rr[2][2]+rr[3][2];
    float m3v = rr[0][3]+rr[1][3]+rr[2][3]+rr[3][3];
    float c0 = rsqrtf(m0v*(1.f/D_) + 1e-6f), c1 = rsqrtf(m1v*(1.f/D_) + 1e-6f);
    float c2 = rsqrtf(m2v*(1.f/D_) + 1e-6f), c3 = rsqrtf(m3v*(1.f/D_) + 1e-6f);
    #pragma unroll
    for (int i = 0; i < 4; i++) {
      int c = tid + i*256;
      float v0 = a0[i]*wv[i]*c0, v1 = a1[i]*wv[i]*c1;
      float v2 = a2[i]*wv[i]*c2, v3 = a3[i]*wv[i]*c3;
      xn[(size_t)(4*j)*D_ + c]          = f2bf(v0);
      xn[(size_t)(4*j)*D_ + D_ + c]     = f2bf(v1);
      xn[(size_t)(4*j)*D_ + 2*D_ + c]   = f2bf(v2);
      xn[(size_t)(4*j)*D_ + 3*D_ + c]   = f2bf(v3);
      xp1[(size_t)(2*j)*D_ + c]         = f2bf(0.5f*(v0 + v1));
      xp1[(size_t)(2*j)*D_ + D_ + c]    = f2bf(0.5f*(v2 + v3));
      xp2[(size_t)j*D_ + c]             = f2bf(0.25f*(v0 + v1 + v2 + v3));
    }
  }
}

// ---------------- MFMA GEMM, C = A[M,K] * BT[N,K]^T; block = MT*32 x 128, BK=64 ----
// Counted-vmcnt dbuf pipeline (R3). MODE 1: bf16 store. MODE 2: fp32 out =
// SCp[11]*X1 + SCp[12]*acc. MODE 3: silu(gate)*up epilogue (BTgu interleaved),
// bf16 h store stride HIDP. MODE 4: QKV epilogue — cols<2048 bf16 store; cols>=2048
// V stored transposed into Cv2 (per-level [b][c][n] layout).
template<int MT, int MODE>
__global__ __launch_bounds__(256, 2) void gemm_t(const u16* __restrict__ A, const u16* __restrict__ BT,
                                                 void* __restrict__ Cv, void* __restrict__ Cv2,
                                                 const float* __restrict__ X1,
                                                 const float* __restrict__ SCp,
                                                 int N, int K, int t1, int t2, unsigned int bt_stride) {
  static_assert(MT == 4 || MT == 2, "vmcnt count assumes MT+4 staging loads");
  __shared__ __align__(16) u16 As[2][MT*32*64];
  __shared__ __align__(16) u16 Bs[2][128*64];
  const int tid = threadIdx.x;
  const int lane = tid & 63, wid = tid >> 6;
  const int quad = lane >> 4, c16 = lane & 15;
  const int y = blockIdx.y;
  const int m0 = y * (MT*32), n0 = blockIdx.x * 128;
  const int wm = wid >> 1, wn = wid & 1;
  const int level = (y >= t2) ? 2 : ((y >= t1) ? 1 : 0);
  BT += (size_t)level * bt_stride;

  f32x4 acc[MT][4];
  #pragma unroll
  for (int i = 0; i < MT; i++)
    #pragma unroll
    for (int j = 0; j < 4; j++) acc[i][j] = f32x4{0.f,0.f,0.f,0.f};

  const int srow = lane >> 3;
  const int schunk = lane & 7;
  auto stage = [&](int k0, int p) {
    #pragma unroll
    for (int t = 0; t < MT; t++) {
      int idx = wid*MT + t;
      int row = idx*8 + srow;
      int g = (schunk ^ (row & 7)) * 8;
      gload_lds16(A + (size_t)(m0+row)*K + k0 + g, &As[p][idx*512]);
    }
    #pragma unroll
    for (int t = 0; t < 4; t++) {
      int idx = wid*4 + t;
      int row = idx*8 + srow;
      int g = (schunk ^ (row & 7)) * 8;
      gload_lds16(BT + (size_t)(n0+row)*K + k0 + g, &Bs[p][idx*512]);
    }
  };

  const int nk = K >> 6;
  stage(0, 0);
  for (int ki = 0; ki < nk; ki++) {
    const int p = ki & 1;
    if (ki + 1 < nk) {
      stage((ki + 1) << 6, p ^ 1);
      if constexpr (MT == 4) asm volatile("s_waitcnt vmcnt(8)" ::: "memory");
      else                   asm volatile("s_waitcnt vmcnt(6)" ::: "memory");
    } else {
      asm volatile("s_waitcnt vmcnt(0)" ::: "memory");
    }
    __builtin_amdgcn_s_barrier();
    __builtin_amdgcn_sched_barrier(0);
    __builtin_amdgcn_s_setprio(1);
    #pragma unroll
    for (int kh = 0; kh < 2; kh++) {
      short8 af[MT], bfr[4];
      #pragma unroll
      for (int mt = 0; mt < MT; mt++) {
        int ar = wm*(MT*16) + mt*16 + c16;
        int ck = (kh*4 + quad) ^ (ar & 7);
        af[mt] = *(const short8*)(&As[p][ar*64 + ck*8]);
      }
      #pragma unroll
      for (int nt = 0; nt < 4; nt++) {
        int br = wn*64 + nt*16 + c16;
        int ck = (kh*4 + quad) ^ (br & 7);
        bfr[nt] = *(const short8*)(&Bs[p][br*64 + ck*8]);
      }
      #pragma unroll
      for (int mt = 0; mt < MT; mt++)
        #pragma unroll
        for (int nt = 0; nt < 4; nt++)
          acc[mt][nt] = __builtin_amdgcn_mfma_f32_16x16x32_bf16(af[mt], bfr[nt], acc[mt][nt], 0, 0, 0);
    }
    __builtin_amdgcn_s_setprio(0);
    __builtin_amdgcn_sched_barrier(0);
    __builtin_amdgcn_s_barrier();
  }
  if (MODE == 1) {
    u16* C = (u16*)Cv;
    #pragma unroll
    for (int mt = 0; mt < MT; mt++)
      #pragma unroll
      for (int nt = 0; nt < 4; nt++)
        #pragma unroll
        for (int r = 0; r < 4; r++) {
          int row = m0 + wm*(MT*16) + mt*16 + quad*4 + r;
          int col = n0 + wn*64 + nt*16 + c16;
          C[(size_t)row * N + col] = f2bf(acc[mt][nt][r]);
        }
  } else if (MODE == 2) {
    float* C = (float*)Cv;
    const float q0 = SCp[11], q1 = SCp[12];
    #pragma unroll
    for (int mt = 0; mt < MT; mt++)
      #pragma unroll
      for (int nt = 0; nt < 4; nt++)
        #pragma unroll
        for (int r = 0; r < 4; r++) {
          int row = m0 + wm*(MT*16) + mt*16 + quad*4 + r;
          int col = n0 + wn*64 + nt*16 + c16;
          size_t o = (size_t)row * N + col;
          C[o] = q0 * X1[o] + q1 * acc[mt][nt][r];
        }
  } else if (MODE == 3) {
    u16* Hc = (u16*)Cv;
    const int hbase = (n0 >> 1) + wn*32;
    #pragma unroll
    for (int mt = 0; mt < MT; mt++)
      #pragma unroll
      for (int r = 0; r < 4; r++) {
        int row = m0 + wm*(MT*16) + mt*16 + quad*4 + r;
        #pragma unroll
        for (int pr = 0; pr < 2; pr++) {
          float g = acc[mt][2*pr][r], u = acc[mt][2*pr+1][r];
          float h = g / (1.f + __expf(-g)) * u;
          Hc[(size_t)row * HIDP + hbase + pr*16 + c16] = f2bf(h);
        }
      }
  } else {  // MODE 4
    if (n0 < 2048) {
      u16* C = (u16*)Cv;
      #pragma unroll
      for (int mt = 0; mt < MT; mt++)
        #pragma unroll
        for (int nt = 0; nt < 4; nt++)
          #pragma unroll
          for (int r = 0; r < 4; r++) {
            int row = m0 + wm*(MT*16) + mt*16 + quad*4 + r;
            int col = n0 + wn*64 + nt*16 + c16;
            C[(size_t)row * N + col] = f2bf(acc[mt][nt][r]);
          }
    } else {
      const int Nl = 2048 >> level;
      const int lvbase = (level==0) ? 0 : (level==1) ? 4096 : 6144;
      const size_t vtoff = (level==0) ? 0 : (level==1) ? 4194304 : 6291456;
      u16* VT = (u16*)Cv2 + vtoff;
      #pragma unroll
      for (int mt = 0; mt < MT; mt++) {
        int rowg = m0 + wm*(MT*16) + mt*16 + quad*4;   // r=0 row; +3 stays in-row-group
        int nloc = rowg - lvbase;
        int b = nloc / Nl;              // Nl is power of two
        int n = nloc - b*Nl;
        #pragma unroll
        for (int nt = 0; nt < 4; nt++) {
          int c = n0 - 2048 + wn*64 + nt*16 + c16;
          u16x4 o;
          o[0]=f2bf(acc[mt][nt][0]); o[1]=f2bf(acc[mt][nt][1]);
          o[2]=f2bf(acc[mt][nt][2]); o[3]=f2bf(acc[mt][nt][3]);
          *(u16x4*)(VT + ((size_t)(b*1024 + c))*Nl + n) = o;
        }
      }
    }
  }
}

// ---------------- MFMA flash attention, all levels merged, no-max online softmax ----
__global__ __launch_bounds__(256) void flash_k(const u16* __restrict__ QKVg,
                                               const u16* __restrict__ VTg,
                                               u16* __restrict__ Og) {
  __shared__ __align__(16) u16 Kt[2][64*64];
  __shared__ __align__(16) u16 Vt[2][64*64];
  __shared__ __align__(16) u16 Ps[4][32*68];
  const int tid = threadIdx.x, lane = tid & 63, wid = tid >> 6;
  const int quad = lane >> 4, c16 = lane & 15;
  const int id = blockIdx.x;
  int qt, bh, Nl, rowbase; size_t vtoff;
  if (id < 512)      { qt = 15 - (id >> 5);            bh = id & 31;  Nl = 2048; rowbase = 0;    vtoff = 0; }
  else if (id < 768) { int t2 = id - 512; qt = 7 - (t2 >> 5); bh = t2 & 31; Nl = 1024; rowbase = 4096; vtoff = 4194304; }
  else               { int t2 = id - 768; qt = 3 - (t2 >> 5); bh = t2 & 31; Nl = 512;  rowbase = 6144; vtoff = 6291456; }
  const int b = bh >> 4, h = bh & 15;
  const u16* QK = QKVg + ((size_t)(rowbase + b*Nl)) * 3072 + h*64;
  u16* Ow = Og + ((size_t)(rowbase + b*Nl)) * 1024 + h*64;
  const u16* VT = VTg + vtoff + ((size_t)b*1024 + h*64) * (size_t)Nl;

  const int q0r = qt*128 + wid*32;
  short8 bq[2][2];
  #pragma unroll
  for (int qh = 0; qh < 2; qh++) {
    const u16* qp = QK + (size_t)(q0r + qh*16 + c16)*3072 + quad*8;
    bq[qh][0] = *(const short8*)qp;
    bq[qh][1] = *(const short8*)(qp + 32);
  }
  const int si0 = wid*2, si1 = si0 + 1;
  const int sr0 = si0*8 + (lane>>3), sr1 = si1*8 + (lane>>3);
  const int sg  = ((lane&7) ^ (lane>>3)) * 8;
  const u16* Ks0 = QK + 1024 + (size_t)sr0*3072 + sg;
  const u16* Ks1 = QK + 1024 + (size_t)sr1*3072 + sg;
  const u16* Vs0 = VT + (size_t)sr0*Nl + sg;
  const u16* Vs1 = VT + (size_t)sr1*Nl + sg;

  f32x4 oacc[2][4];
  f32x4 lacc[2];
  #pragma unroll
  for (int qh = 0; qh < 2; qh++) {
    lacc[qh] = f32x4{0.f,0.f,0.f,0.f};
    #pragma unroll
    for (int nt = 0; nt < 4; nt++) oacc[qh][nt] = f32x4{0.f,0.f,0.f,0.f};
  }

  auto stage = [&](int kt, int p) {
    const size_t ko = (size_t)kt * 64;
    gload_lds16(Ks0 + ko*3072, &Kt[p][si0*512]);
    gload_lds16(Ks1 + ko*3072, &Kt[p][si1*512]);
    gload_lds16(Vs0 + ko,      &Vt[p][si0*512]);
    gload_lds16(Vs1 + ko,      &Vt[p][si1*512]);
  };
  const int kmax_w = 2*qt + (wid >> 1);
  const int ktot   = 2*qt + 2;
  stage(0, 0);

  for (int kt = 0; kt < ktot; kt++) {
    const int p = kt & 1;
    __syncthreads();
    if (kt + 1 < ktot) stage(kt+1, p^1);
    if (kt > kmax_w) continue;

    f32x4 st[2][4];
    #pragma unroll
    for (int nt = 0; nt < 4; nt++) {
      int key = nt*16 + c16, x = key & 7;
      short8 a0 = *(const short8*)(&Kt[p][key*64 + ((quad    ) ^ x)*8]);
      short8 a1 = *(const short8*)(&Kt[p][key*64 + ((quad + 4) ^ x)*8]);
      #pragma unroll
      for (int qh = 0; qh < 2; qh++) {
        f32x4 s = f32x4{0.f,0.f,0.f,0.f};
        s = __builtin_amdgcn_mfma_f32_16x16x32_bf16(a0, bq[qh][0], s, 0, 0, 0);
        s = __builtin_amdgcn_mfma_f32_16x16x32_bf16(a1, bq[qh][1], s, 0, 0, 0);
        st[qh][nt] = s;
      }
    }
    if (kt >= 2*qt) {
      const int kb = kt*64;
      #pragma unroll
      for (int qh = 0; qh < 2; qh++) {
        const int qr = q0r + qh*16 + c16;
        #pragma unroll
        for (int nt = 0; nt < 4; nt++) {
          #pragma unroll
          for (int r = 0; r < 4; r++) {
            float e = __builtin_amdgcn_exp2f(st[qh][nt][r]);
            st[qh][nt][r] = (kb + nt*16 + quad*4 + r <= qr) ? e : 0.f;
          }
          lacc[qh] += st[qh][nt];
        }
      }
    } else {
      #pragma unroll
      for (int qh = 0; qh < 2; qh++)
        #pragma unroll
        for (int nt = 0; nt < 4; nt++) {
          #pragma unroll
          for (int r = 0; r < 4; r++) st[qh][nt][r] = __builtin_amdgcn_exp2f(st[qh][nt][r]);
          lacc[qh] += st[qh][nt];
        }
    }
    #pragma unroll
    for (int qh = 0; qh < 2; qh++) {
      const int prow = qh*16 + c16;
      #pragma unroll
      for (int nt = 0; nt < 4; nt++) {
        uint2 pk;
        pk.x = pkbf(st[qh][nt][0], st[qh][nt][1]);
        pk.y = pkbf(st[qh][nt][2], st[qh][nt][3]);
        *(uint2*)(&Ps[wid][prow*68 + nt*16 + quad*4]) = pk;
      }
    }
    short8 bp[2][2];
    #pragma unroll
    for (int qh = 0; qh < 2; qh++) {
      bp[qh][0] = *(const short8*)(&Ps[wid][(qh*16 + c16)*68 +      quad*8]);
      bp[qh][1] = *(const short8*)(&Ps[wid][(qh*16 + c16)*68 + 32 + quad*8]);
    }
    #pragma unroll
    for (int nt = 0; nt < 4; nt++) {
      int dh = nt*16 + c16, x = dh & 7;
      short8 a0 = *(const short8*)(&Vt[p][dh*64 + ((quad    ) ^ x)*8]);
      short8 a1 = *(const short8*)(&Vt[p][dh*64 + ((quad + 4) ^ x)*8]);
      #pragma unroll
      for (int qh = 0; qh < 2; qh++) {
        oacc[qh][nt] = __builtin_amdgcn_mfma_f32_16x16x32_bf16(a0, bp[qh][0], oacc[qh][nt], 0, 0, 0);
        oacc[qh][nt] = __builtin_amdgcn_mfma_f32_16x16x32_bf16(a1, bp[qh][1], oacc[qh][nt], 0, 0, 0);
      }
    }
  }
  #pragma unroll
  for (int qh = 0; qh < 2; qh++) {
    float ls = lacc[qh][0] + lacc[qh][1] + lacc[qh][2] + lacc[qh][3];
    ls += __shfl_xor(ls, 16);
    ls += __shfl_xor(ls, 32);
    const float rl = 1.f / ls;
    #pragma unroll
    for (int nt = 0; nt < 4; nt++) {
      uint2 o;
      o.x = pkbf(oacc[qh][nt][0]*rl, oacc[qh][nt][1]*rl);
      o.y = pkbf(oacc[qh][nt][2]*rl, oacc[qh][nt][3]*rl);
      *(uint2*)(Ow + (size_t)(q0r + qh*16 + c16)*1024 + nt*16 + quad*4) = o;
    }
  }
}

// -------- Gram matrix over repeat map (bf16 Y) + inline head on last block --------
__global__ __launch_bounds__(256) void gramhead_k(const u16* __restrict__ Y0, const u16* __restrict__ Y1,
                                                  const u16* __restrict__ Y2, float* __restrict__ G,
                                                  int* __restrict__ done,
                                                  const float* __restrict__ agg, const float* __restrict__ mA,
                                                  const float* __restrict__ mF, float* __restrict__ aux_out) {
  float a[6] = {0,0,0,0,0,0};
  const int total4 = CNT/4;
  for (int i = blockIdx.x*256 + threadIdx.x; i < total4; i += gridDim.x*256) {
    int d4 = i & 255; int n = (i >> 8) & (N_-1); int b = i >> 19;
    u16x4 y0v = *(const u16x4*)(Y0 + (size_t)i*4);
    u16x4 y1v = *(const u16x4*)(Y1 + (((size_t)(b*1024 + (n>>1))) << 10) + d4*4);
    u16x4 y2v = *(const u16x4*)(Y2 + (((size_t)(b*512  + (n>>2))) << 10) + d4*4);
    #pragma unroll
    for (int t = 0; t < 4; t++) {
      float y0 = bf2f(y0v[t]), y1 = bf2f(y1v[t]), y2 = bf2f(y2v[t]);
      a[0] += y0*y0; a[1] += y0*y1; a[2] += y0*y2;
      a[3] += y1*y1; a[4] += y1*y2; a[5] += y2*y2;
    }
  }
  __shared__ float red[4][6];
  const int lane = threadIdx.x & 63, wid = threadIdx.x >> 6;
  #pragma unroll
  for (int t = 0; t < 6; t++) {
    float v = a[t];
    v += __shfl_xor(v, 1);  v += __shfl_xor(v, 2);  v += __shfl_xor(v, 4);
    v += __shfl_xor(v, 8);  v += __shfl_xor(v, 16); v += __shfl_xor(v, 32);
    a[t] = v;
  }
  if (lane == 0)
    #pragma unroll
    for (int t = 0; t < 6; t++) red[wid][t] = a[t];
  __syncthreads();
  if (threadIdx.x < 6)
    atomicAdd(&G[threadIdx.x], red[0][threadIdx.x] + red[1][threadIdx.x] +
                               red[2][threadIdx.x] + red[3][threadIdx.x]);
  // ---- last finishing block computes Nash + Sinkhorn head inline ----
  __threadfence();
  __shared__ int lastf;
  if (threadIdx.x == 0) lastf = (atomicAdd(done, 1) == (int)gridDim.x - 1);
  __syncthreads();
  if (lastf && threadIdx.x == 0) {
    float Gv[6];
    for (int t = 0; t < 6; t++)
      Gv[t] = __hip_atomic_load(&G[t], __ATOMIC_RELAXED, __HIP_MEMORY_SCOPE_AGENT);
    float* SC = G;
    const int gi[3][3] = {{0,1,2},{1,3,4},{2,4,5}};
    float av[3] = {agg[0], agg[1], agg[2]};
    float w[3];
    {
      float m = fmaxf(av[0], fmaxf(av[1], av[2])); float s = 0.f;
      for (int l = 0; l < 3; l++) { w[l] = expf(av[l]-m); s += w[l]; }
      for (int l = 0; l < 3; l++) w[l] /= s;
    }
    const float inv = 1.f / (float)CNT;
    for (int it = 0; it < 3; it++) {
      float q = 0.f;
      for (int l = 0; l < 3; l++) for (int m2 = 0; m2 < 3; m2++) q += w[l]*w[m2]*Gv[gi[l][m2]];
      float z[3];
      for (int l = 0; l < 3; l++) {
        float dot = w[0]*Gv[gi[l][0]] + w[1]*Gv[gi[l][1]] + w[2]*Gv[gi[l][2]];
        z[l] = av[l] - (Gv[gi[l][l]] - 2.f*dot + q) * inv;
      }
      float m = fmaxf(z[0], fmaxf(z[1], z[2])); float s = 0.f;
      for (int l = 0; l < 3; l++) { w[l] = expf(z[l]-m); s += w[l]; }
      for (int l = 0; l < 3; l++) w[l] /= s;
    }
    SC[6] = w[0]; SC[7] = w[1]; SC[8] = w[2];
    aux_out[0] = w[0]*logf(w[0]*3.f + 1e-9f) + w[1]*logf(w[1]*3.f + 1e-9f) + w[2]*logf(w[2]*3.f + 1e-9f);
    for (int which = 0; which < 2; which++) {
      const float* Lg = which ? mF : mA;
      float M0 = expf(Lg[0]), M1 = expf(Lg[1]), M2 = expf(Lg[2]), M3 = expf(Lg[3]);
      for (int i2 = 0; i2 < 10; i2++) {
        float r0 = M0+M1, r1 = M2+M3; M0 /= r0; M1 /= r0; M2 /= r1; M3 /= r1;
        float c0 = M0+M2, c1 = M1+M3; M0 /= c0; M2 /= c0; M1 /= c1; M3 /= c1;
      }
      SC[9 + which*2] = M0; SC[10 + which*2] = M1;
    }
  }
}

// ---------------- fused mix1 + FFN RMSNorm: one row per block ----------------
__global__ __launch_bounds__(256) void mixrms_k(const float* __restrict__ x, const u16* __restrict__ Y0,
                                                const u16* __restrict__ Y1, const u16* __restrict__ Y2,
                                                const float* __restrict__ SC, const float* __restrict__ w2,
                                                float* __restrict__ x1, u16* __restrict__ xn2) {
  const float w0 = SC[6], w1 = SC[7], ww2 = SC[8], p0 = SC[9], p1 = SC[10];
  const int i = blockIdx.x;
  const int b = i >> 11, n = i & 2047;
  const float* xr = x + (size_t)i * D_;
  const u16* y0 = Y0 + (size_t)i * D_;
  const u16* y1 = Y1 + (size_t)(b*1024 + (n>>1)) * D_;
  const u16* y2 = Y2 + (size_t)(b*512  + (n>>2)) * D_;
  float xv[4], wv[4];
  float ss = 0.f;
  #pragma unroll
  for (int t = 0; t < 4; t++) {
    int c = threadIdx.x + t*256;
    float v = p0*xr[c] + p1*(w0*bf2f(y0[c]) + w1*bf2f(y1[c]) + ww2*bf2f(y2[c]));
    xv[t] = v; wv[t] = w2[c]; ss += v*v;
    x1[(size_t)i*D_ + c] = v;
  }
  #pragma unroll
  for (int o = 1; o < 64; o <<= 1) ss += __shfl_xor(ss, o);
  __shared__ float red[4];
  if ((threadIdx.x & 63) == 0) red[threadIdx.x >> 6] = ss;
  __syncthreads();
  float sc = rsqrtf((red[0]+red[1]+red[2]+red[3]) * (1.f/D_) + 1e-6f);
  #pragma unroll
  for (int t = 0; t < 4; t++) {
    int c = threadIdx.x + t*256;
    xn2[(size_t)i*D_ + c] = f2bf(xv[t]*wv[t]*sc);
  }
}

// ================================ host launcher ================================
extern "C" void kernel_launch(void* const* d_in, const int* in_sizes, int n_in,
                              void* d_out, int out_size, void* d_ws, size_t ws_size,
                              hipStream_t stream) {
  (void)in_sizes; (void)n_in; (void)out_size; (void)ws_size;
  const float* x    = (const float*)d_in[0];
  const float* nw1  = (const float*)d_in[1];
  const float* nw2  = (const float*)d_in[2];
  const float* Wdec = (const float*)d_in[3];
  const float* Wq   = (const float*)d_in[4];
  const float* Wk   = (const float*)d_in[5];
  const float* Wv   = (const float*)d_in[6];
  const float* Wo   = (const float*)d_in[7];
  const float* agg  = (const float*)d_in[8];
  const float* Wg   = (const float*)d_in[9];
  const float* Wu   = (const float*)d_in[10];
  const float* Wdn  = (const float*)d_in[11];
  const float* mA   = (const float*)d_in[12];
  const float* mF   = (const float*)d_in[13];
  float* out = (float*)d_out;

  char* ws = (char*)d_ws;
  size_t off = 0;
  auto take = [&](size_t b) { size_t r = off; off += (b + 255) & ~(size_t)255; return r; };

  u16* A_wp  = (u16*)(ws + take((size_t)9216*1024*2));
  u16* WdecB = (u16*)(ws + take((size_t)3*1024*1024*2));
  u16* Wqkv  = (u16*)(ws + take((size_t)9216*1024*2));
  u16* BTgu  = (u16*)(ws + take((size_t)5632*1024*2));   // gate/up 16-col interleaved
  u16* WdnT  = (u16*)(ws + take((size_t)HIDP*1024*2));
  u16* WoT   = (u16*)(ws + take((size_t)1024*1024*2));
  u16* xn_all = (u16*)(ws + take((size_t)7168*1024*2));
  float* x1  = (float*)(ws + take((size_t)CNT*4));
  float* SCb = (float*)(ws + take(256));
  char*  big = ws + take(88080384);
  // attention phase
  u16*   QKV   = (u16*)big;                              // [7168, 3072] bf16 (V cols unused)
  u16*   VTa   = (u16*)(big + 44040192);                 // per-level [b][1024][Nl]
  u16*   Ob    = (u16*)(big + 58720256);                 // [7168, 1024] bf16
  u16*   YC    = (u16*)(big + 73400320);                 // [7168, 1024] bf16
  // FFN phase alias (attention working set dead by then; YC region untouched)
  u16*   hbuf  = (u16*)big;                              // [4096, 2816] bf16

  u16* xp1 = xn_all + (size_t)4096*1024;
  u16* xp2 = xn_all + (size_t)6144*1024;
  int* done = (int*)SCb + 15;          // zeroed with SCb each replay

  dim3 blk(256);
  const int BIG = 1 << 30;

  // ---- 1: QKV weight transposes + Wdec convert + SCb zero ----
  wprep1_k<<<12288, blk, 0, stream>>>(Wdec, Wq, Wk, Wv, A_wp, WdecB, SCb);
  // ---- 2: MEGA — wqkv GEMM (576) + Wo/Wg/Wu/Wdn transposes + pad + rmsA4 ----
  mega_k<<<11236, blk, 0, stream>>>(A_wp, WdecB, Wqkv, Wo, Wg, Wu, Wdn,
                                    WoT, BTgu, WdnT, x, nw1, xn_all, xp1, xp2);
  // ---- 3: QKV GEMM (per-level weight select) + fused V transpose epilogue ----
  gemm_t<4,4><<<dim3(24, 56), blk, 0, stream>>>(xn_all, Wqkv, QKV, VTa, nullptr, nullptr,
                                                3072, 1024, 32, 48, 3072u*1024u);
  // ---- 4: flash attention (all levels) ----
  flash_k<<<896, blk, 0, stream>>>(QKV, VTa, Ob);
  // ---- 5: output projection -> YC (bf16) ----
  gemm_t<4,1><<<dim3(8, 56), blk, 0, stream>>>(Ob, WoT, YC, nullptr, nullptr, nullptr,
                                               1024, 1024, BIG, BIG, 0u);
  // ---- 6: Nash via Gram + inline head on last block ----
  u16* YC1 = YC + (size_t)4096*1024;
  u16* YC2 = YC + (size_t)6144*1024;
  gramhead_k<<<1024, blk, 0, stream>>>(YC, YC1, YC2, SCb, done, agg, mA, mF, out + CNT);
  // ---- 7: mix1 + FFN RMSNorm fused ----
  mixrms_k<<<4096, blk, 0, stream>>>(x, YC, YC1, YC2, SCb, nw2, x1, xn_all);
  // ---- 8: gate/up GEMM with fused silu*mul epilogue ----
  gemm_t<4,3><<<dim3(44, 32), blk, 0, stream>>>(xn_all, BTgu, hbuf, nullptr, nullptr, nullptr,
                                                5632, 1024, BIG, BIG, 0u);
  // ---- 9: down GEMM, MT=2 (512 blocks -> all CUs), fused final residual mix ----
  gemm_t<2,2><<<dim3(8, 64), blk, 0, stream>>>(hbuf, WdnT, out, nullptr, x1, SCb,
                                               1024, HIDP, BIG, BIG, 0u);
}

// Round 7
// 519.787 us; speedup vs baseline: 1.0311x; 1.0311x over previous
//
#include <hip/hip_runtime.h>
#include <stdint.h>

// MAHA decoder block, MI355X/gfx950. Round 12: best-of reassembly —
// R3 GEMM (counted vmcnt, grid dispatch) for all 5 GEMMs; rmsA4 (4-row RMSNorm
// + both pool levels in-register) folded into wprep_k (resource-compatible:
// all memory-bound small-LDS blocks); gram+head fused; down-proj MT=2 (512 blocks).
// Mega-launch of R6 reverted (GEMM LDS/VGPR envelope starved co-resident blocks).
// B=2, N=2048, D=1024, H=16(dh=64), L=3, R=2, HID=2734(->2816), fp32 I/O.

#define B_   2
#define N_   2048
#define D_   1024
#define H_   16
#define DH_  64
#define HID_ 2734
#define HIDP 2816
#define CNT  (B_*N_*D_)   // 4194304
#define LOG2E 1.4426950408889634f

typedef unsigned short u16;
typedef __attribute__((ext_vector_type(8))) short short8;
typedef __attribute__((ext_vector_type(4))) float f32x4;
typedef __attribute__((ext_vector_type(4))) uint16_t u16x4;

__device__ __forceinline__ u16 f2bf(float f) {
  uint32_t u = __builtin_bit_cast(uint32_t, f);
  u += 0x7fffu + ((u >> 16) & 1u);          // RNE
  return (u16)(u >> 16);
}
__device__ __forceinline__ float bf2f(u16 h) {
  uint32_t u = ((uint32_t)h) << 16;
  return __builtin_bit_cast(float, u);
}
__device__ __forceinline__ uint32_t pkbf(float a, float b) {
  return (uint32_t)f2bf(a) | ((uint32_t)f2bf(b) << 16);
}
__device__ __forceinline__ void gload_lds16(const void* g, void* l) {
  __builtin_amdgcn_global_load_lds(
      (const __attribute__((address_space(1))) uint32_t*)g,
      (__attribute__((address_space(3))) uint32_t*)l, 16, 0, 0);
}

// ============ batched prep: all weight transposes + Wdec convert + SC zero + rmsA4 ====
// blocks: [0,9216) QKV weight transposes | [9216,10240) Wo | [10240,13056) Wg(gate-ilv)
// [13056,15872) Wu(up-ilv) | [15872,18688) Wdn | [18688,21760) Wdec convert (+SC zero)
// [21760,21924) BTgu pad zero | [21924,22948) rmsA4: 4 rows RMSNorm + pool1 + pool2
__global__ __launch_bounds__(256) void wprep_k(const float* __restrict__ Wdec, const float* __restrict__ Wq,
                                               const float* __restrict__ Wk, const float* __restrict__ Wv,
                                               const float* __restrict__ Wo, const float* __restrict__ Wg,
                                               const float* __restrict__ Wu, const float* __restrict__ Wdn,
                                               u16* __restrict__ A_wp, u16* __restrict__ WdecB,
                                               u16* __restrict__ WoT, u16* __restrict__ BTgu,
                                               u16* __restrict__ WdnT, float* __restrict__ SCb,
                                               const float* __restrict__ x, const float* __restrict__ nw1,
                                               u16* __restrict__ xn, u16* __restrict__ xp1,
                                               u16* __restrict__ xp2) {
  const int bid = blockIdx.x;
  const int tid = threadIdx.x;
  if (bid >= 21924) {
    // ---- rmsA4: 4 rows per block, both pool levels in-register ----
    const int j = bid - 21924;
    const float* xr = x + (size_t)(4*j) * D_;
    float a0[4], a1[4], a2[4], a3[4], wv[4];
    float s0=0.f, s1=0.f, s2=0.f, s3=0.f;
    #pragma unroll
    for (int i = 0; i < 4; i++) {
      int c = tid + i*256;
      wv[i] = nw1[c];
      a0[i] = xr[c]; a1[i] = xr[D_+c]; a2[i] = xr[2*D_+c]; a3[i] = xr[3*D_+c];
      s0 += a0[i]*a0[i]; s1 += a1[i]*a1[i]; s2 += a2[i]*a2[i]; s3 += a3[i]*a3[i];
    }
    #pragma unroll
    for (int o = 1; o < 64; o <<= 1) {
      s0 += __shfl_xor(s0, o); s1 += __shfl_xor(s1, o);
      s2 += __shfl_xor(s2, o); s3 += __shfl_xor(s3, o);
    }
    __shared__ float rr[4][4];
    if ((tid & 63) == 0) { int w = tid >> 6; rr[w][0]=s0; rr[w][1]=s1; rr[w][2]=s2; rr[w][3]=s3; }
    __syncthreads();
    float m0v = rr[0][0]+rr[1][0]+rr[2][0]+rr[3][0];
    float m1v = rr[0][1]+rr[1][1]+rr[2][1]+rr[3][1];
    float m2v = rr[0][2]+rr[1][2]+rr[2][2]+rr[3][2];
    float m3v = rr[0][3]+rr[1][3]+rr[2][3]+rr[3][3];
    float c0 = rsqrtf(m0v*(1.f/D_) + 1e-6f), c1 = rsqrtf(m1v*(1.f/D_) + 1e-6f);
    float c2 = rsqrtf(m2v*(1.f/D_) + 1e-6f), c3 = rsqrtf(m3v*(1.f/D_) + 1e-6f);
    #pragma unroll
    for (int i = 0; i < 4; i++) {
      int c = tid + i*256;
      float v0 = a0[i]*wv[i]*c0, v1 = a1[i]*wv[i]*c1;
      float v2 = a2[i]*wv[i]*c2, v3 = a3[i]*wv[i]*c3;
      xn[(size_t)(4*j)*D_ + c]        = f2bf(v0);
      xn[(size_t)(4*j)*D_ + D_ + c]   = f2bf(v1);
      xn[(size_t)(4*j)*D_ + 2*D_ + c] = f2bf(v2);
      xn[(size_t)(4*j)*D_ + 3*D_ + c] = f2bf(v3);
      xp1[(size_t)(2*j)*D_ + c]       = f2bf(0.5f*(v0 + v1));
      xp1[(size_t)(2*j)*D_ + D_ + c]  = f2bf(0.5f*(v2 + v3));
      xp2[(size_t)j*D_ + c]           = f2bf(0.25f*(v0 + v1 + v2 + v3));
    }
    return;
  }
  if (bid >= 21760) {
    int bid0 = bid - 21760;
    int row = (bid0 < 2) ? (5454 + bid0) : (5470 + (bid0 - 2));
    u16x4 zz; zz[0]=0; zz[1]=0; zz[2]=0; zz[3]=0;
    *(u16x4*)(BTgu + (size_t)row*1024 + tid*4) = zz;
    return;
  }
  if (bid >= 18688) {
    if (bid == 18688 && tid < 64) SCb[tid] = 0.f;
    int i = (bid - 18688)*1024 + tid*4;
    float4 v = *(const float4*)(Wdec + i);
    u16x4 o; o[0]=f2bf(v.x); o[1]=f2bf(v.y); o[2]=f2bf(v.z); o[3]=f2bf(v.w);
    *(u16x4*)(WdecB + i) = o;
    return;
  }
  const float* src; u16* dst; int K, N, KP; float scale; int imode; int bx, by;
  if (bid < 9216) {
    int j = bid >> 10, t = bid & 1023; bx = t & 31; by = t >> 5;
    int l = j / 3, which = j - l*3;
    src = which==0 ? Wq + (size_t)l*1048576 : which==1 ? Wk + (size_t)l*1048576 : Wv;
    dst = A_wp + (size_t)(l*3072 + which*1024)*1024;
    K = 1024; N = 1024; KP = 1024; scale = (which==0) ? 0.125f*LOG2E : 1.f; imode = 0;
  } else if (bid < 10240) {
    int t = bid - 9216; bx = t & 31; by = t >> 5;
    src = Wo; dst = WoT; K=1024; N=1024; KP=1024; scale=1.f; imode=0;
  } else if (bid < 13056) {
    int t = bid - 10240; bx = t % 88; by = t / 88;
    src = Wg; dst = BTgu; K=1024; N=HID_; KP=1024; scale=1.f; imode=1;
  } else if (bid < 15872) {
    int t = bid - 13056; bx = t % 88; by = t / 88;
    src = Wu; dst = BTgu; K=1024; N=HID_; KP=1024; scale=1.f; imode=2;
  } else {
    int t = bid - 15872; bx = t & 31; by = t >> 5;
    src = Wdn; dst = WdnT; K=HID_; N=1024; KP=HIDP; scale=1.f; imode=0;
  }
  __shared__ float tt[32][33];
  const int tx = tid & 31, ty = tid >> 5;
  const int nb = bx*32, kb = by*32;
  #pragma unroll
  for (int i = 0; i < 4; i++) {
    int k = kb + ty + i*8, n = nb + tx;
    tt[ty + i*8][tx] = (k < K && n < N) ? src[(size_t)k * N + n] * scale : 0.f;
  }
  __syncthreads();
  #pragma unroll
  for (int i = 0; i < 4; i++) {
    int n = nb + ty + i*8, k = kb + tx;
    int r;
    if (imode == 0) r = n;
    else if (imode == 1) r = ((n>>4)<<5) + (n&15);
    else r = ((n>>4)<<5) + 16 + (n&15);
    dst[(size_t)r * KP + k] = f2bf(tt[tx][ty + i*8]);
  }
}

// ---------------- MFMA GEMM, C = A[M,K] * BT[N,K]^T; block = MT*32 x 128, BK=64 ----
// Counted-vmcnt dbuf pipeline (R3 best-measured). MODE 1: bf16 store. MODE 2: fp32
// out = SCp[11]*X1 + SCp[12]*acc. MODE 3: silu(gate)*up epilogue (BTgu interleaved),
// bf16 h store stride HIDP. MODE 4: QKV epilogue — cols<2048 bf16 store; cols>=2048
// V stored transposed into Cv2 (per-level [b][c][n] layout).
template<int MT, int MODE>
__global__ __launch_bounds__(256, 2) void gemm_t(const u16* __restrict__ A, const u16* __restrict__ BT,
                                                 void* __restrict__ Cv, void* __restrict__ Cv2,
                                                 const float* __restrict__ X1,
                                                 const float* __restrict__ SCp,
                                                 int N, int K, int t1, int t2, unsigned int bt_stride) {
  static_assert(MT == 4 || MT == 2, "vmcnt count assumes MT+4 staging loads");
  __shared__ __align__(16) u16 As[2][MT*32*64];
  __shared__ __align__(16) u16 Bs[2][128*64];
  const int tid = threadIdx.x;
  const int lane = tid & 63, wid = tid >> 6;
  const int quad = lane >> 4, c16 = lane & 15;
  const int y = blockIdx.y;
  const int m0 = y * (MT*32), n0 = blockIdx.x * 128;
  const int wm = wid >> 1, wn = wid & 1;
  const int level = (y >= t2) ? 2 : ((y >= t1) ? 1 : 0);
  BT += (size_t)level * bt_stride;

  f32x4 acc[MT][4];
  #pragma unroll
  for (int i = 0; i < MT; i++)
    #pragma unroll
    for (int j = 0; j < 4; j++) acc[i][j] = f32x4{0.f,0.f,0.f,0.f};

  const int srow = lane >> 3;
  const int schunk = lane & 7;
  auto stage = [&](int k0, int p) {
    #pragma unroll
    for (int t = 0; t < MT; t++) {
      int idx = wid*MT + t;
      int row = idx*8 + srow;
      int g = (schunk ^ (row & 7)) * 8;
      gload_lds16(A + (size_t)(m0+row)*K + k0 + g, &As[p][idx*512]);
    }
    #pragma unroll
    for (int t = 0; t < 4; t++) {
      int idx = wid*4 + t;
      int row = idx*8 + srow;
      int g = (schunk ^ (row & 7)) * 8;
      gload_lds16(BT + (size_t)(n0+row)*K + k0 + g, &Bs[p][idx*512]);
    }
  };

  const int nk = K >> 6;
  stage(0, 0);
  for (int ki = 0; ki < nk; ki++) {
    const int p = ki & 1;
    if (ki + 1 < nk) {
      stage((ki + 1) << 6, p ^ 1);
      if constexpr (MT == 4) asm volatile("s_waitcnt vmcnt(8)" ::: "memory");
      else                   asm volatile("s_waitcnt vmcnt(6)" ::: "memory");
    } else {
      asm volatile("s_waitcnt vmcnt(0)" ::: "memory");
    }
    __builtin_amdgcn_s_barrier();
    __builtin_amdgcn_sched_barrier(0);
    __builtin_amdgcn_s_setprio(1);
    #pragma unroll
    for (int kh = 0; kh < 2; kh++) {
      short8 af[MT], bfr[4];
      #pragma unroll
      for (int mt = 0; mt < MT; mt++) {
        int ar = wm*(MT*16) + mt*16 + c16;
        int ck = (kh*4 + quad) ^ (ar & 7);
        af[mt] = *(const short8*)(&As[p][ar*64 + ck*8]);
      }
      #pragma unroll
      for (int nt = 0; nt < 4; nt++) {
        int br = wn*64 + nt*16 + c16;
        int ck = (kh*4 + quad) ^ (br & 7);
        bfr[nt] = *(const short8*)(&Bs[p][br*64 + ck*8]);
      }
      #pragma unroll
      for (int mt = 0; mt < MT; mt++)
        #pragma unroll
        for (int nt = 0; nt < 4; nt++)
          acc[mt][nt] = __builtin_amdgcn_mfma_f32_16x16x32_bf16(af[mt], bfr[nt], acc[mt][nt], 0, 0, 0);
    }
    __builtin_amdgcn_s_setprio(0);
    __builtin_amdgcn_sched_barrier(0);
    __builtin_amdgcn_s_barrier();
  }
  if (MODE == 1) {
    u16* C = (u16*)Cv;
    #pragma unroll
    for (int mt = 0; mt < MT; mt++)
      #pragma unroll
      for (int nt = 0; nt < 4; nt++)
        #pragma unroll
        for (int r = 0; r < 4; r++) {
          int row = m0 + wm*(MT*16) + mt*16 + quad*4 + r;
          int col = n0 + wn*64 + nt*16 + c16;
          C[(size_t)row * N + col] = f2bf(acc[mt][nt][r]);
        }
  } else if (MODE == 2) {
    float* C = (float*)Cv;
    const float q0 = SCp[11], q1 = SCp[12];
    #pragma unroll
    for (int mt = 0; mt < MT; mt++)
      #pragma unroll
      for (int nt = 0; nt < 4; nt++)
        #pragma unroll
        for (int r = 0; r < 4; r++) {
          int row = m0 + wm*(MT*16) + mt*16 + quad*4 + r;
          int col = n0 + wn*64 + nt*16 + c16;
          size_t o = (size_t)row * N + col;
          C[o] = q0 * X1[o] + q1 * acc[mt][nt][r];
        }
  } else if (MODE == 3) {
    u16* Hc = (u16*)Cv;
    const int hbase = (n0 >> 1) + wn*32;
    #pragma unroll
    for (int mt = 0; mt < MT; mt++)
      #pragma unroll
      for (int r = 0; r < 4; r++) {
        int row = m0 + wm*(MT*16) + mt*16 + quad*4 + r;
        #pragma unroll
        for (int pr = 0; pr < 2; pr++) {
          float g = acc[mt][2*pr][r], u = acc[mt][2*pr+1][r];
          float h = g / (1.f + __expf(-g)) * u;
          Hc[(size_t)row * HIDP + hbase + pr*16 + c16] = f2bf(h);
        }
      }
  } else {  // MODE 4
    if (n0 < 2048) {
      u16* C = (u16*)Cv;
      #pragma unroll
      for (int mt = 0; mt < MT; mt++)
        #pragma unroll
        for (int nt = 0; nt < 4; nt++)
          #pragma unroll
          for (int r = 0; r < 4; r++) {
            int row = m0 + wm*(MT*16) + mt*16 + quad*4 + r;
            int col = n0 + wn*64 + nt*16 + c16;
            C[(size_t)row * N + col] = f2bf(acc[mt][nt][r]);
          }
    } else {
      const int Nl = 2048 >> level;
      const int lvbase = (level==0) ? 0 : (level==1) ? 4096 : 6144;
      const size_t vtoff = (level==0) ? 0 : (level==1) ? 4194304 : 6291456;
      u16* VT = (u16*)Cv2 + vtoff;
      #pragma unroll
      for (int mt = 0; mt < MT; mt++) {
        int rowg = m0 + wm*(MT*16) + mt*16 + quad*4;   // r=0 row; +3 stays in-row-group
        int nloc = rowg - lvbase;
        int b = nloc / Nl;              // Nl is power of two
        int n = nloc - b*Nl;
        #pragma unroll
        for (int nt = 0; nt < 4; nt++) {
          int c = n0 - 2048 + wn*64 + nt*16 + c16;
          u16x4 o;
          o[0]=f2bf(acc[mt][nt][0]); o[1]=f2bf(acc[mt][nt][1]);
          o[2]=f2bf(acc[mt][nt][2]); o[3]=f2bf(acc[mt][nt][3]);
          *(u16x4*)(VT + ((size_t)(b*1024 + c))*Nl + n) = o;
        }
      }
    }
  }
}

// ---------------- MFMA flash attention, all levels merged, no-max online softmax ----
__global__ __launch_bounds__(256) void flash_k(const u16* __restrict__ QKVg,
                                               const u16* __restrict__ VTg,
                                               u16* __restrict__ Og) {
  __shared__ __align__(16) u16 Kt[2][64*64];
  __shared__ __align__(16) u16 Vt[2][64*64];
  __shared__ __align__(16) u16 Ps[4][32*68];
  const int tid = threadIdx.x, lane = tid & 63, wid = tid >> 6;
  const int quad = lane >> 4, c16 = lane & 15;
  const int id = blockIdx.x;
  int qt, bh, Nl, rowbase; size_t vtoff;
  if (id < 512)      { qt = 15 - (id >> 5);            bh = id & 31;  Nl = 2048; rowbase = 0;    vtoff = 0; }
  else if (id < 768) { int t2 = id - 512; qt = 7 - (t2 >> 5); bh = t2 & 31; Nl = 1024; rowbase = 4096; vtoff = 4194304; }
  else               { int t2 = id - 768; qt = 3 - (t2 >> 5); bh = t2 & 31; Nl = 512;  rowbase = 6144; vtoff = 6291456; }
  const int b = bh >> 4, h = bh & 15;
  const u16* QK = QKVg + ((size_t)(rowbase + b*Nl)) * 3072 + h*64;
  u16* Ow = Og + ((size_t)(rowbase + b*Nl)) * 1024 + h*64;
  const u16* VT = VTg + vtoff + ((size_t)b*1024 + h*64) * (size_t)Nl;

  const int q0r = qt*128 + wid*32;
  short8 bq[2][2];
  #pragma unroll
  for (int qh = 0; qh < 2; qh++) {
    const u16* qp = QK + (size_t)(q0r + qh*16 + c16)*3072 + quad*8;
    bq[qh][0] = *(const short8*)qp;
    bq[qh][1] = *(const short8*)(qp + 32);
  }
  const int si0 = wid*2, si1 = si0 + 1;
  const int sr0 = si0*8 + (lane>>3), sr1 = si1*8 + (lane>>3);
  const int sg  = ((lane&7) ^ (lane>>3)) * 8;
  const u16* Ks0 = QK + 1024 + (size_t)sr0*3072 + sg;
  const u16* Ks1 = QK + 1024 + (size_t)sr1*3072 + sg;
  const u16* Vs0 = VT + (size_t)sr0*Nl + sg;
  const u16* Vs1 = VT + (size_t)sr1*Nl + sg;

  f32x4 oacc[2][4];
  f32x4 lacc[2];
  #pragma unroll
  for (int qh = 0; qh < 2; qh++) {
    lacc[qh] = f32x4{0.f,0.f,0.f,0.f};
    #pragma unroll
    for (int nt = 0; nt < 4; nt++) oacc[qh][nt] = f32x4{0.f,0.f,0.f,0.f};
  }

  auto stage = [&](int kt, int p) {
    const size_t ko = (size_t)kt * 64;
    gload_lds16(Ks0 + ko*3072, &Kt[p][si0*512]);
    gload_lds16(Ks1 + ko*3072, &Kt[p][si1*512]);
    gload_lds16(Vs0 + ko,      &Vt[p][si0*512]);
    gload_lds16(Vs1 + ko,      &Vt[p][si1*512]);
  };
  const int kmax_w = 2*qt + (wid >> 1);
  const int ktot   = 2*qt + 2;
  stage(0, 0);

  for (int kt = 0; kt < ktot; kt++) {
    const int p = kt & 1;
    __syncthreads();
    if (kt + 1 < ktot) stage(kt+1, p^1);
    if (kt > kmax_w) continue;

    f32x4 st[2][4];
    #pragma unroll
    for (int nt = 0; nt < 4; nt++) {
      int key = nt*16 + c16, x = key & 7;
      short8 a0 = *(const short8*)(&Kt[p][key*64 + ((quad    ) ^ x)*8]);
      short8 a1 = *(const short8*)(&Kt[p][key*64 + ((quad + 4) ^ x)*8]);
      #pragma unroll
      for (int qh = 0; qh < 2; qh++) {
        f32x4 s = f32x4{0.f,0.f,0.f,0.f};
        s = __builtin_amdgcn_mfma_f32_16x16x32_bf16(a0, bq[qh][0], s, 0, 0, 0);
        s = __builtin_amdgcn_mfma_f32_16x16x32_bf16(a1, bq[qh][1], s, 0, 0, 0);
        st[qh][nt] = s;
      }
    }
    if (kt >= 2*qt) {
      const int kb = kt*64;
      #pragma unroll
      for (int qh = 0; qh < 2; qh++) {
        const int qr = q0r + qh*16 + c16;
        #pragma unroll
        for (int nt = 0; nt < 4; nt++) {
          #pragma unroll
          for (int r = 0; r < 4; r++) {
            float e = __builtin_amdgcn_exp2f(st[qh][nt][r]);
            st[qh][nt][r] = (kb + nt*16 + quad*4 + r <= qr) ? e : 0.f;
          }
          lacc[qh] += st[qh][nt];
        }
      }
    } else {
      #pragma unroll
      for (int qh = 0; qh < 2; qh++)
        #pragma unroll
        for (int nt = 0; nt < 4; nt++) {
          #pragma unroll
          for (int r = 0; r < 4; r++) st[qh][nt][r] = __builtin_amdgcn_exp2f(st[qh][nt][r]);
          lacc[qh] += st[qh][nt];
        }
    }
    #pragma unroll
    for (int qh = 0; qh < 2; qh++) {
      const int prow = qh*16 + c16;
      #pragma unroll
      for (int nt = 0; nt < 4; nt++) {
        uint2 pk;
        pk.x = pkbf(st[qh][nt][0], st[qh][nt][1]);
        pk.y = pkbf(st[qh][nt][2], st[qh][nt][3]);
        *(uint2*)(&Ps[wid][prow*68 + nt*16 + quad*4]) = pk;
      }
    }
    short8 bp[2][2];
    #pragma unroll
    for (int qh = 0; qh < 2; qh++) {
      bp[qh][0] = *(const short8*)(&Ps[wid][(qh*16 + c16)*68 +      quad*8]);
      bp[qh][1] = *(const short8*)(&Ps[wid][(qh*16 + c16)*68 + 32 + quad*8]);
    }
    #pragma unroll
    for (int nt = 0; nt < 4; nt++) {
      int dh = nt*16 + c16, x = dh & 7;
      short8 a0 = *(const short8*)(&Vt[p][dh*64 + ((quad    ) ^ x)*8]);
      short8 a1 = *(const short8*)(&Vt[p][dh*64 + ((quad + 4) ^ x)*8]);
      #pragma unroll
      for (int qh = 0; qh < 2; qh++) {
        oacc[qh][nt] = __builtin_amdgcn_mfma_f32_16x16x32_bf16(a0, bp[qh][0], oacc[qh][nt], 0, 0, 0);
        oacc[qh][nt] = __builtin_amdgcn_mfma_f32_16x16x32_bf16(a1, bp[qh][1], oacc[qh][nt], 0, 0, 0);
      }
    }
  }
  #pragma unroll
  for (int qh = 0; qh < 2; qh++) {
    float ls = lacc[qh][0] + lacc[qh][1] + lacc[qh][2] + lacc[qh][3];
    ls += __shfl_xor(ls, 16);
    ls += __shfl_xor(ls, 32);
    const float rl = 1.f / ls;
    #pragma unroll
    for (int nt = 0; nt < 4; nt++) {
      uint2 o;
      o.x = pkbf(oacc[qh][nt][0]*rl, oacc[qh][nt][1]*rl);
      o.y = pkbf(oacc[qh][nt][2]*rl, oacc[qh][nt][3]*rl);
      *(uint2*)(Ow + (size_t)(q0r + qh*16 + c16)*1024 + nt*16 + quad*4) = o;
    }
  }
}

// -------- Gram matrix over repeat map (bf16 Y) + inline head on last block --------
__global__ __launch_bounds__(256) void gramhead_k(const u16* __restrict__ Y0, const u16* __restrict__ Y1,
                                                  const u16* __restrict__ Y2, float* __restrict__ G,
                                                  int* __restrict__ done,
                                                  const float* __restrict__ agg, const float* __restrict__ mA,
                                                  const float* __restrict__ mF, float* __restrict__ aux_out) {
  float a[6] = {0,0,0,0,0,0};
  const int total4 = CNT/4;
  for (int i = blockIdx.x*256 + threadIdx.x; i < total4; i += gridDim.x*256) {
    int d4 = i & 255; int n = (i >> 8) & (N_-1); int b = i >> 19;
    u16x4 y0v = *(const u16x4*)(Y0 + (size_t)i*4);
    u16x4 y1v = *(const u16x4*)(Y1 + (((size_t)(b*1024 + (n>>1))) << 10) + d4*4);
    u16x4 y2v = *(const u16x4*)(Y2 + (((size_t)(b*512  + (n>>2))) << 10) + d4*4);
    #pragma unroll
    for (int t = 0; t < 4; t++) {
      float y0 = bf2f(y0v[t]), y1 = bf2f(y1v[t]), y2 = bf2f(y2v[t]);
      a[0] += y0*y0; a[1] += y0*y1; a[2] += y0*y2;
      a[3] += y1*y1; a[4] += y1*y2; a[5] += y2*y2;
    }
  }
  __shared__ float red[4][6];
  const int lane = threadIdx.x & 63, wid = threadIdx.x >> 6;
  #pragma unroll
  for (int t = 0; t < 6; t++) {
    float v = a[t];
    v += __shfl_xor(v, 1);  v += __shfl_xor(v, 2);  v += __shfl_xor(v, 4);
    v += __shfl_xor(v, 8);  v += __shfl_xor(v, 16); v += __shfl_xor(v, 32);
    a[t] = v;
  }
  if (lane == 0)
    #pragma unroll
    for (int t = 0; t < 6; t++) red[wid][t] = a[t];
  __syncthreads();
  if (threadIdx.x < 6)
    atomicAdd(&G[threadIdx.x], red[0][threadIdx.x] + red[1][threadIdx.x] +
                               red[2][threadIdx.x] + red[3][threadIdx.x]);
  // ---- last finishing block computes Nash + Sinkhorn head inline ----
  __threadfence();
  __shared__ int lastf;
  if (threadIdx.x == 0) lastf = (atomicAdd(done, 1) == (int)gridDim.x - 1);
  __syncthreads();
  if (lastf && threadIdx.x == 0) {
    float Gv[6];
    for (int t = 0; t < 6; t++)
      Gv[t] = __hip_atomic_load(&G[t], __ATOMIC_RELAXED, __HIP_MEMORY_SCOPE_AGENT);
    float* SC = G;
    const int gi[3][3] = {{0,1,2},{1,3,4},{2,4,5}};
    float av[3] = {agg[0], agg[1], agg[2]};
    float w[3];
    {
      float m = fmaxf(av[0], fmaxf(av[1], av[2])); float s = 0.f;
      for (int l = 0; l < 3; l++) { w[l] = expf(av[l]-m); s += w[l]; }
      for (int l = 0; l < 3; l++) w[l] /= s;
    }
    const float inv = 1.f / (float)CNT;
    for (int it = 0; it < 3; it++) {
      float q = 0.f;
      for (int l = 0; l < 3; l++) for (int m2 = 0; m2 < 3; m2++) q += w[l]*w[m2]*Gv[gi[l][m2]];
      float z[3];
      for (int l = 0; l < 3; l++) {
        float dot = w[0]*Gv[gi[l][0]] + w[1]*Gv[gi[l][1]] + w[2]*Gv[gi[l][2]];
        z[l] = av[l] - (Gv[gi[l][l]] - 2.f*dot + q) * inv;
      }
      float m = fmaxf(z[0], fmaxf(z[1], z[2])); float s = 0.f;
      for (int l = 0; l < 3; l++) { w[l] = expf(z[l]-m); s += w[l]; }
      for (int l = 0; l < 3; l++) w[l] /= s;
    }
    SC[6] = w[0]; SC[7] = w[1]; SC[8] = w[2];
    aux_out[0] = w[0]*logf(w[0]*3.f + 1e-9f) + w[1]*logf(w[1]*3.f + 1e-9f) + w[2]*logf(w[2]*3.f + 1e-9f);
    for (int which = 0; which < 2; which++) {
      const float* Lg = which ? mF : mA;
      float M0 = expf(Lg[0]), M1 = expf(Lg[1]), M2 = expf(Lg[2]), M3 = expf(Lg[3]);
      for (int i2 = 0; i2 < 10; i2++) {
        float r0 = M0+M1, r1 = M2+M3; M0 /= r0; M1 /= r0; M2 /= r1; M3 /= r1;
        float c0 = M0+M2, c1 = M1+M3; M0 /= c0; M2 /= c0; M1 /= c1; M3 /= c1;
      }
      SC[9 + which*2] = M0; SC[10 + which*2] = M1;
    }
  }
}

// ---------------- fused mix1 + FFN RMSNorm: one row per block ----------------
__global__ __launch_bounds__(256) void mixrms_k(const float* __restrict__ x, const u16* __restrict__ Y0,
                                                const u16* __restrict__ Y1, const u16* __restrict__ Y2,
                                                const float* __restrict__ SC, const float* __restrict__ w2,
                                                float* __restrict__ x1, u16* __restrict__ xn2) {
  const float w0 = SC[6], w1 = SC[7], ww2 = SC[8], p0 = SC[9], p1 = SC[10];
  const int i = blockIdx.x;
  const int b = i >> 11, n = i & 2047;
  const float* xr = x + (size_t)i * D_;
  const u16* y0 = Y0 + (size_t)i * D_;
  const u16* y1 = Y1 + (size_t)(b*1024 + (n>>1)) * D_;
  const u16* y2 = Y2 + (size_t)(b*512  + (n>>2)) * D_;
  float xv[4], wv[4];
  float ss = 0.f;
  #pragma unroll
  for (int t = 0; t < 4; t++) {
    int c = threadIdx.x + t*256;
    float v = p0*xr[c] + p1*(w0*bf2f(y0[c]) + w1*bf2f(y1[c]) + ww2*bf2f(y2[c]));
    xv[t] = v; wv[t] = w2[c]; ss += v*v;
    x1[(size_t)i*D_ + c] = v;
  }
  #pragma unroll
  for (int o = 1; o < 64; o <<= 1) ss += __shfl_xor(ss, o);
  __shared__ float red[4];
  if ((threadIdx.x & 63) == 0) red[threadIdx.x >> 6] = ss;
  __syncthreads();
  float sc = rsqrtf((red[0]+red[1]+red[2]+red[3]) * (1.f/D_) + 1e-6f);
  #pragma unroll
  for (int t = 0; t < 4; t++) {
    int c = threadIdx.x + t*256;
    xn2[(size_t)i*D_ + c] = f2bf(xv[t]*wv[t]*sc);
  }
}

// ================================ host launcher ================================
extern "C" void kernel_launch(void* const* d_in, const int* in_sizes, int n_in,
                              void* d_out, int out_size, void* d_ws, size_t ws_size,
                              hipStream_t stream) {
  (void)in_sizes; (void)n_in; (void)out_size; (void)ws_size;
  const float* x    = (const float*)d_in[0];
  const float* nw1  = (const float*)d_in[1];
  const float* nw2  = (const float*)d_in[2];
  const float* Wdec = (const float*)d_in[3];
  const float* Wq   = (const float*)d_in[4];
  const float* Wk   = (const float*)d_in[5];
  const float* Wv   = (const float*)d_in[6];
  const float* Wo   = (const float*)d_in[7];
  const float* agg  = (const float*)d_in[8];
  const float* Wg   = (const float*)d_in[9];
  const float* Wu   = (const float*)d_in[10];
  const float* Wdn  = (const float*)d_in[11];
  const float* mA   = (const float*)d_in[12];
  const float* mF   = (const float*)d_in[13];
  float* out = (float*)d_out;

  char* ws = (char*)d_ws;
  size_t off = 0;
  auto take = [&](size_t b) { size_t r = off; off += (b + 255) & ~(size_t)255; return r; };

  u16* A_wp  = (u16*)(ws + take((size_t)9216*1024*2));
  u16* WdecB = (u16*)(ws + take((size_t)3*1024*1024*2));
  u16* Wqkv  = (u16*)(ws + take((size_t)9216*1024*2));
  u16* BTgu  = (u16*)(ws + take((size_t)5632*1024*2));   // gate/up 16-col interleaved
  u16* WdnT  = (u16*)(ws + take((size_t)HIDP*1024*2));
  u16* WoT   = (u16*)(ws + take((size_t)1024*1024*2));
  u16* xn_all = (u16*)(ws + take((size_t)7168*1024*2));
  float* x1  = (float*)(ws + take((size_t)CNT*4));
  float* SCb = (float*)(ws + take(256));
  char*  big = ws + take(88080384);
  // attention phase
  u16*   QKV   = (u16*)big;                              // [7168, 3072] bf16 (V cols unused)
  u16*   VTa   = (u16*)(big + 44040192);                 // per-level [b][1024][Nl]
  u16*   Ob    = (u16*)(big + 58720256);                 // [7168, 1024] bf16
  u16*   YC    = (u16*)(big + 73400320);                 // [7168, 1024] bf16
  // FFN phase alias (attention working set dead by then; YC region untouched)
  u16*   hbuf  = (u16*)big;                              // [4096, 2816] bf16

  u16* xp1 = xn_all + (size_t)4096*1024;
  u16* xp2 = xn_all + (size_t)6144*1024;
  int* done = (int*)SCb + 15;          // zeroed with SCb each replay

  dim3 blk(256);
  const int BIG = 1 << 30;

  // ---- 1: all weight prep + SCb zero + BTgu pad + rmsA4 (norm + both pools) ----
  wprep_k<<<22948, blk, 0, stream>>>(Wdec, Wq, Wk, Wv, Wo, Wg, Wu, Wdn,
                                     A_wp, WdecB, WoT, BTgu, WdnT, SCb,
                                     x, nw1, xn_all, xp1, xp2);
  // ---- 2: fused QKV weights: F_l^T = [Wq|Wk|Wv]_l^T x Wdec_l^T ----
  gemm_t<4,1><<<dim3(8, 72), blk, 0, stream>>>(A_wp, WdecB, Wqkv, nullptr, nullptr, nullptr,
                                               1024, 1024, 24, 48, 1024u*1024u);
  // ---- 3: QKV GEMM (per-level weight select) + fused V transpose epilogue ----
  gemm_t<4,4><<<dim3(24, 56), blk, 0, stream>>>(xn_all, Wqkv, QKV, VTa, nullptr, nullptr,
                                                3072, 1024, 32, 48, 3072u*1024u);
  // ---- 4: flash attention (all levels) ----
  flash_k<<<896, blk, 0, stream>>>(QKV, VTa, Ob);
  // ---- 5: output projection -> YC (bf16) ----
  gemm_t<4,1><<<dim3(8, 56), blk, 0, stream>>>(Ob, WoT, YC, nullptr, nullptr, nullptr,
                                               1024, 1024, BIG, BIG, 0u);
  // ---- 6: Nash via Gram + inline head on last block ----
  u16* YC1 = YC + (size_t)4096*1024;
  u16* YC2 = YC + (size_t)6144*1024;
  gramhead_k<<<1024, blk, 0, stream>>>(YC, YC1, YC2, SCb, done, agg, mA, mF, out + CNT);
  // ---- 7: mix1 + FFN RMSNorm fused ----
  mixrms_k<<<4096, blk, 0, stream>>>(x, YC, YC1, YC2, SCb, nw2, x1, xn_all);
  // ---- 8: gate/up GEMM with fused silu*mul epilogue ----
  gemm_t<4,3><<<dim3(44, 32), blk, 0, stream>>>(xn_all, BTgu, hbuf, nullptr, nullptr, nullptr,
                                                5632, 1024, BIG, BIG, 0u);
  // ---- 9: down GEMM, MT=2 (512 blocks -> all CUs, 2/CU), fused final residual mix ----
  gemm_t<2,2><<<dim3(8, 64), blk, 0, stream>>>(hbuf, WdnT, out, nullptr, x1, SCb,
                                               1024, HIDP, BIG, BIG, 0u);
}

// Round 8
// 480.150 us; speedup vs baseline: 1.1163x; 1.0826x over previous
//
#include <hip/hip_runtime.h>
#include <stdint.h>

// MAHA decoder block, MI355X/gfx950. Round 13: gram de-serialization —
// gram_k writes per-block partials (plain stores, no same-line atomics);
// separate 1-block head_k reduces + Nash/Sinkhorn (kernel boundary = sync).
// R7's gramhead fusion removed (1024 same-cacheline atomics = ~70us serial).
// Down-proj reverted to R3 MT=4/256-block. rmsA4 stays folded in wprep_k.
// B=2, N=2048, D=1024, H=16(dh=64), L=3, R=2, HID=2734(->2816), fp32 I/O.

#define B_   2
#define N_   2048
#define D_   1024
#define H_   16
#define DH_  64
#define HID_ 2734
#define HIDP 2816
#define CNT  (B_*N_*D_)   // 4194304
#define LOG2E 1.4426950408889634f

typedef unsigned short u16;
typedef __attribute__((ext_vector_type(8))) short short8;
typedef __attribute__((ext_vector_type(4))) float f32x4;
typedef __attribute__((ext_vector_type(4))) uint16_t u16x4;
typedef __attribute__((ext_vector_type(8))) uint16_t u16x8;

__device__ __forceinline__ u16 f2bf(float f) {
  uint32_t u = __builtin_bit_cast(uint32_t, f);
  u += 0x7fffu + ((u >> 16) & 1u);          // RNE
  return (u16)(u >> 16);
}
__device__ __forceinline__ float bf2f(u16 h) {
  uint32_t u = ((uint32_t)h) << 16;
  return __builtin_bit_cast(float, u);
}
__device__ __forceinline__ uint32_t pkbf(float a, float b) {
  return (uint32_t)f2bf(a) | ((uint32_t)f2bf(b) << 16);
}
__device__ __forceinline__ void gload_lds16(const void* g, void* l) {
  __builtin_amdgcn_global_load_lds(
      (const __attribute__((address_space(1))) uint32_t*)g,
      (__attribute__((address_space(3))) uint32_t*)l, 16, 0, 0);
}

// ============ batched prep: all weight transposes + Wdec convert + SC zero + rmsA4 ====
// blocks: [0,9216) QKV weight transposes | [9216,10240) Wo | [10240,13056) Wg(gate-ilv)
// [13056,15872) Wu(up-ilv) | [15872,18688) Wdn | [18688,21760) Wdec convert (+SC zero)
// [21760,21924) BTgu pad zero | [21924,22948) rmsA4: 4 rows RMSNorm + pool1 + pool2
__global__ __launch_bounds__(256) void wprep_k(const float* __restrict__ Wdec, const float* __restrict__ Wq,
                                               const float* __restrict__ Wk, const float* __restrict__ Wv,
                                               const float* __restrict__ Wo, const float* __restrict__ Wg,
                                               const float* __restrict__ Wu, const float* __restrict__ Wdn,
                                               u16* __restrict__ A_wp, u16* __restrict__ WdecB,
                                               u16* __restrict__ WoT, u16* __restrict__ BTgu,
                                               u16* __restrict__ WdnT, float* __restrict__ SCb,
                                               const float* __restrict__ x, const float* __restrict__ nw1,
                                               u16* __restrict__ xn, u16* __restrict__ xp1,
                                               u16* __restrict__ xp2) {
  const int bid = blockIdx.x;
  const int tid = threadIdx.x;
  if (bid >= 21924) {
    // ---- rmsA4: 4 rows per block, both pool levels in-register ----
    const int j = bid - 21924;
    const float* xr = x + (size_t)(4*j) * D_;
    float a0[4], a1[4], a2[4], a3[4], wv[4];
    float s0=0.f, s1=0.f, s2=0.f, s3=0.f;
    #pragma unroll
    for (int i = 0; i < 4; i++) {
      int c = tid + i*256;
      wv[i] = nw1[c];
      a0[i] = xr[c]; a1[i] = xr[D_+c]; a2[i] = xr[2*D_+c]; a3[i] = xr[3*D_+c];
      s0 += a0[i]*a0[i]; s1 += a1[i]*a1[i]; s2 += a2[i]*a2[i]; s3 += a3[i]*a3[i];
    }
    #pragma unroll
    for (int o = 1; o < 64; o <<= 1) {
      s0 += __shfl_xor(s0, o); s1 += __shfl_xor(s1, o);
      s2 += __shfl_xor(s2, o); s3 += __shfl_xor(s3, o);
    }
    __shared__ float rr[4][4];
    if ((tid & 63) == 0) { int w = tid >> 6; rr[w][0]=s0; rr[w][1]=s1; rr[w][2]=s2; rr[w][3]=s3; }
    __syncthreads();
    float m0v = rr[0][0]+rr[1][0]+rr[2][0]+rr[3][0];
    float m1v = rr[0][1]+rr[1][1]+rr[2][1]+rr[3][1];
    float m2v = rr[0][2]+rr[1][2]+rr[2][2]+rr[3][2];
    float m3v = rr[0][3]+rr[1][3]+rr[2][3]+rr[3][3];
    float c0 = rsqrtf(m0v*(1.f/D_) + 1e-6f), c1 = rsqrtf(m1v*(1.f/D_) + 1e-6f);
    float c2 = rsqrtf(m2v*(1.f/D_) + 1e-6f), c3 = rsqrtf(m3v*(1.f/D_) + 1e-6f);
    #pragma unroll
    for (int i = 0; i < 4; i++) {
      int c = tid + i*256;
      float v0 = a0[i]*wv[i]*c0, v1 = a1[i]*wv[i]*c1;
      float v2 = a2[i]*wv[i]*c2, v3 = a3[i]*wv[i]*c3;
      xn[(size_t)(4*j)*D_ + c]        = f2bf(v0);
      xn[(size_t)(4*j)*D_ + D_ + c]   = f2bf(v1);
      xn[(size_t)(4*j)*D_ + 2*D_ + c] = f2bf(v2);
      xn[(size_t)(4*j)*D_ + 3*D_ + c] = f2bf(v3);
      xp1[(size_t)(2*j)*D_ + c]       = f2bf(0.5f*(v0 + v1));
      xp1[(size_t)(2*j)*D_ + D_ + c]  = f2bf(0.5f*(v2 + v3));
      xp2[(size_t)j*D_ + c]           = f2bf(0.25f*(v0 + v1 + v2 + v3));
    }
    return;
  }
  if (bid >= 21760) {
    int bid0 = bid - 21760;
    int row = (bid0 < 2) ? (5454 + bid0) : (5470 + (bid0 - 2));
    u16x4 zz; zz[0]=0; zz[1]=0; zz[2]=0; zz[3]=0;
    *(u16x4*)(BTgu + (size_t)row*1024 + tid*4) = zz;
    return;
  }
  if (bid >= 18688) {
    if (bid == 18688 && tid < 64) SCb[tid] = 0.f;
    int i = (bid - 18688)*1024 + tid*4;
    float4 v = *(const float4*)(Wdec + i);
    u16x4 o; o[0]=f2bf(v.x); o[1]=f2bf(v.y); o[2]=f2bf(v.z); o[3]=f2bf(v.w);
    *(u16x4*)(WdecB + i) = o;
    return;
  }
  const float* src; u16* dst; int K, N, KP; float scale; int imode; int bx, by;
  if (bid < 9216) {
    int j = bid >> 10, t = bid & 1023; bx = t & 31; by = t >> 5;
    int l = j / 3, which = j - l*3;
    src = which==0 ? Wq + (size_t)l*1048576 : which==1 ? Wk + (size_t)l*1048576 : Wv;
    dst = A_wp + (size_t)(l*3072 + which*1024)*1024;
    K = 1024; N = 1024; KP = 1024; scale = (which==0) ? 0.125f*LOG2E : 1.f; imode = 0;
  } else if (bid < 10240) {
    int t = bid - 9216; bx = t & 31; by = t >> 5;
    src = Wo; dst = WoT; K=1024; N=1024; KP=1024; scale=1.f; imode=0;
  } else if (bid < 13056) {
    int t = bid - 10240; bx = t % 88; by = t / 88;
    src = Wg; dst = BTgu; K=1024; N=HID_; KP=1024; scale=1.f; imode=1;
  } else if (bid < 15872) {
    int t = bid - 13056; bx = t % 88; by = t / 88;
    src = Wu; dst = BTgu; K=1024; N=HID_; KP=1024; scale=1.f; imode=2;
  } else {
    int t = bid - 15872; bx = t & 31; by = t >> 5;
    src = Wdn; dst = WdnT; K=HID_; N=1024; KP=HIDP; scale=1.f; imode=0;
  }
  __shared__ float tt[32][33];
  const int tx = tid & 31, ty = tid >> 5;
  const int nb = bx*32, kb = by*32;
  #pragma unroll
  for (int i = 0; i < 4; i++) {
    int k = kb + ty + i*8, n = nb + tx;
    tt[ty + i*8][tx] = (k < K && n < N) ? src[(size_t)k * N + n] * scale : 0.f;
  }
  __syncthreads();
  #pragma unroll
  for (int i = 0; i < 4; i++) {
    int n = nb + ty + i*8, k = kb + tx;
    int r;
    if (imode == 0) r = n;
    else if (imode == 1) r = ((n>>4)<<5) + (n&15);
    else r = ((n>>4)<<5) + 16 + (n&15);
    dst[(size_t)r * KP + k] = f2bf(tt[tx][ty + i*8]);
  }
}

// ---------------- MFMA GEMM, C = A[M,K] * BT[N,K]^T; block = MT*32 x 128, BK=64 ----
// Counted-vmcnt dbuf pipeline (R3 best-measured). MODE 1: bf16 store. MODE 2: fp32
// out = SCp[11]*X1 + SCp[12]*acc. MODE 3: silu(gate)*up epilogue (BTgu interleaved),
// bf16 h store stride HIDP. MODE 4: QKV epilogue — cols<2048 bf16 store; cols>=2048
// V stored transposed into Cv2 (per-level [b][c][n] layout).
template<int MT, int MODE>
__global__ __launch_bounds__(256, 2) void gemm_t(const u16* __restrict__ A, const u16* __restrict__ BT,
                                                 void* __restrict__ Cv, void* __restrict__ Cv2,
                                                 const float* __restrict__ X1,
                                                 const float* __restrict__ SCp,
                                                 int N, int K, int t1, int t2, unsigned int bt_stride) {
  static_assert(MT == 4 || MT == 2, "vmcnt count assumes MT+4 staging loads");
  __shared__ __align__(16) u16 As[2][MT*32*64];
  __shared__ __align__(16) u16 Bs[2][128*64];
  const int tid = threadIdx.x;
  const int lane = tid & 63, wid = tid >> 6;
  const int quad = lane >> 4, c16 = lane & 15;
  const int y = blockIdx.y;
  const int m0 = y * (MT*32), n0 = blockIdx.x * 128;
  const int wm = wid >> 1, wn = wid & 1;
  const int level = (y >= t2) ? 2 : ((y >= t1) ? 1 : 0);
  BT += (size_t)level * bt_stride;

  f32x4 acc[MT][4];
  #pragma unroll
  for (int i = 0; i < MT; i++)
    #pragma unroll
    for (int j = 0; j < 4; j++) acc[i][j] = f32x4{0.f,0.f,0.f,0.f};

  const int srow = lane >> 3;
  const int schunk = lane & 7;
  auto stage = [&](int k0, int p) {
    #pragma unroll
    for (int t = 0; t < MT; t++) {
      int idx = wid*MT + t;
      int row = idx*8 + srow;
      int g = (schunk ^ (row & 7)) * 8;
      gload_lds16(A + (size_t)(m0+row)*K + k0 + g, &As[p][idx*512]);
    }
    #pragma unroll
    for (int t = 0; t < 4; t++) {
      int idx = wid*4 + t;
      int row = idx*8 + srow;
      int g = (schunk ^ (row & 7)) * 8;
      gload_lds16(BT + (size_t)(n0+row)*K + k0 + g, &Bs[p][idx*512]);
    }
  };

  const int nk = K >> 6;
  stage(0, 0);
  for (int ki = 0; ki < nk; ki++) {
    const int p = ki & 1;
    if (ki + 1 < nk) {
      stage((ki + 1) << 6, p ^ 1);
      if constexpr (MT == 4) asm volatile("s_waitcnt vmcnt(8)" ::: "memory");
      else                   asm volatile("s_waitcnt vmcnt(6)" ::: "memory");
    } else {
      asm volatile("s_waitcnt vmcnt(0)" ::: "memory");
    }
    __builtin_amdgcn_s_barrier();
    __builtin_amdgcn_sched_barrier(0);
    __builtin_amdgcn_s_setprio(1);
    #pragma unroll
    for (int kh = 0; kh < 2; kh++) {
      short8 af[MT], bfr[4];
      #pragma unroll
      for (int mt = 0; mt < MT; mt++) {
        int ar = wm*(MT*16) + mt*16 + c16;
        int ck = (kh*4 + quad) ^ (ar & 7);
        af[mt] = *(const short8*)(&As[p][ar*64 + ck*8]);
      }
      #pragma unroll
      for (int nt = 0; nt < 4; nt++) {
        int br = wn*64 + nt*16 + c16;
        int ck = (kh*4 + quad) ^ (br & 7);
        bfr[nt] = *(const short8*)(&Bs[p][br*64 + ck*8]);
      }
      #pragma unroll
      for (int mt = 0; mt < MT; mt++)
        #pragma unroll
        for (int nt = 0; nt < 4; nt++)
          acc[mt][nt] = __builtin_amdgcn_mfma_f32_16x16x32_bf16(af[mt], bfr[nt], acc[mt][nt], 0, 0, 0);
    }
    __builtin_amdgcn_s_setprio(0);
    __builtin_amdgcn_sched_barrier(0);
    __builtin_amdgcn_s_barrier();
  }
  if (MODE == 1) {
    u16* C = (u16*)Cv;
    #pragma unroll
    for (int mt = 0; mt < MT; mt++)
      #pragma unroll
      for (int nt = 0; nt < 4; nt++)
        #pragma unroll
        for (int r = 0; r < 4; r++) {
          int row = m0 + wm*(MT*16) + mt*16 + quad*4 + r;
          int col = n0 + wn*64 + nt*16 + c16;
          C[(size_t)row * N + col] = f2bf(acc[mt][nt][r]);
        }
  } else if (MODE == 2) {
    float* C = (float*)Cv;
    const float q0 = SCp[11], q1 = SCp[12];
    #pragma unroll
    for (int mt = 0; mt < MT; mt++)
      #pragma unroll
      for (int nt = 0; nt < 4; nt++)
        #pragma unroll
        for (int r = 0; r < 4; r++) {
          int row = m0 + wm*(MT*16) + mt*16 + quad*4 + r;
          int col = n0 + wn*64 + nt*16 + c16;
          size_t o = (size_t)row * N + col;
          C[o] = q0 * X1[o] + q1 * acc[mt][nt][r];
        }
  } else if (MODE == 3) {
    u16* Hc = (u16*)Cv;
    const int hbase = (n0 >> 1) + wn*32;
    #pragma unroll
    for (int mt = 0; mt < MT; mt++)
      #pragma unroll
      for (int r = 0; r < 4; r++) {
        int row = m0 + wm*(MT*16) + mt*16 + quad*4 + r;
        #pragma unroll
        for (int pr = 0; pr < 2; pr++) {
          float g = acc[mt][2*pr][r], u = acc[mt][2*pr+1][r];
          float h = g / (1.f + __expf(-g)) * u;
          Hc[(size_t)row * HIDP + hbase + pr*16 + c16] = f2bf(h);
        }
      }
  } else {  // MODE 4
    if (n0 < 2048) {
      u16* C = (u16*)Cv;
      #pragma unroll
      for (int mt = 0; mt < MT; mt++)
        #pragma unroll
        for (int nt = 0; nt < 4; nt++)
          #pragma unroll
          for (int r = 0; r < 4; r++) {
            int row = m0 + wm*(MT*16) + mt*16 + quad*4 + r;
            int col = n0 + wn*64 + nt*16 + c16;
            C[(size_t)row * N + col] = f2bf(acc[mt][nt][r]);
          }
    } else {
      const int Nl = 2048 >> level;
      const int lvbase = (level==0) ? 0 : (level==1) ? 4096 : 6144;
      const size_t vtoff = (level==0) ? 0 : (level==1) ? 4194304 : 6291456;
      u16* VT = (u16*)Cv2 + vtoff;
      #pragma unroll
      for (int mt = 0; mt < MT; mt++) {
        int rowg = m0 + wm*(MT*16) + mt*16 + quad*4;   // r=0 row; +3 stays in-row-group
        int nloc = rowg - lvbase;
        int b = nloc / Nl;              // Nl is power of two
        int n = nloc - b*Nl;
        #pragma unroll
        for (int nt = 0; nt < 4; nt++) {
          int c = n0 - 2048 + wn*64 + nt*16 + c16;
          u16x4 o;
          o[0]=f2bf(acc[mt][nt][0]); o[1]=f2bf(acc[mt][nt][1]);
          o[2]=f2bf(acc[mt][nt][2]); o[3]=f2bf(acc[mt][nt][3]);
          *(u16x4*)(VT + ((size_t)(b*1024 + c))*Nl + n) = o;
        }
      }
    }
  }
}

// ---------------- MFMA flash attention, all levels merged, no-max online softmax ----
__global__ __launch_bounds__(256) void flash_k(const u16* __restrict__ QKVg,
                                               const u16* __restrict__ VTg,
                                               u16* __restrict__ Og) {
  __shared__ __align__(16) u16 Kt[2][64*64];
  __shared__ __align__(16) u16 Vt[2][64*64];
  __shared__ __align__(16) u16 Ps[4][32*68];
  const int tid = threadIdx.x, lane = tid & 63, wid = tid >> 6;
  const int quad = lane >> 4, c16 = lane & 15;
  const int id = blockIdx.x;
  int qt, bh, Nl, rowbase; size_t vtoff;
  if (id < 512)      { qt = 15 - (id >> 5);            bh = id & 31;  Nl = 2048; rowbase = 0;    vtoff = 0; }
  else if (id < 768) { int t2 = id - 512; qt = 7 - (t2 >> 5); bh = t2 & 31; Nl = 1024; rowbase = 4096; vtoff = 4194304; }
  else               { int t2 = id - 768; qt = 3 - (t2 >> 5); bh = t2 & 31; Nl = 512;  rowbase = 6144; vtoff = 6291456; }
  const int b = bh >> 4, h = bh & 15;
  const u16* QK = QKVg + ((size_t)(rowbase + b*Nl)) * 3072 + h*64;
  u16* Ow = Og + ((size_t)(rowbase + b*Nl)) * 1024 + h*64;
  const u16* VT = VTg + vtoff + ((size_t)b*1024 + h*64) * (size_t)Nl;

  const int q0r = qt*128 + wid*32;
  short8 bq[2][2];
  #pragma unroll
  for (int qh = 0; qh < 2; qh++) {
    const u16* qp = QK + (size_t)(q0r + qh*16 + c16)*3072 + quad*8;
    bq[qh][0] = *(const short8*)qp;
    bq[qh][1] = *(const short8*)(qp + 32);
  }
  const int si0 = wid*2, si1 = si0 + 1;
  const int sr0 = si0*8 + (lane>>3), sr1 = si1*8 + (lane>>3);
  const int sg  = ((lane&7) ^ (lane>>3)) * 8;
  const u16* Ks0 = QK + 1024 + (size_t)sr0*3072 + sg;
  const u16* Ks1 = QK + 1024 + (size_t)sr1*3072 + sg;
  const u16* Vs0 = VT + (size_t)sr0*Nl + sg;
  const u16* Vs1 = VT + (size_t)sr1*Nl + sg;

  f32x4 oacc[2][4];
  f32x4 lacc[2];
  #pragma unroll
  for (int qh = 0; qh < 2; qh++) {
    lacc[qh] = f32x4{0.f,0.f,0.f,0.f};
    #pragma unroll
    for (int nt = 0; nt < 4; nt++) oacc[qh][nt] = f32x4{0.f,0.f,0.f,0.f};
  }

  auto stage = [&](int kt, int p) {
    const size_t ko = (size_t)kt * 64;
    gload_lds16(Ks0 + ko*3072, &Kt[p][si0*512]);
    gload_lds16(Ks1 + ko*3072, &Kt[p][si1*512]);
    gload_lds16(Vs0 + ko,      &Vt[p][si0*512]);
    gload_lds16(Vs1 + ko,      &Vt[p][si1*512]);
  };
  const int kmax_w = 2*qt + (wid >> 1);
  const int ktot   = 2*qt + 2;
  stage(0, 0);

  for (int kt = 0; kt < ktot; kt++) {
    const int p = kt & 1;
    __syncthreads();
    if (kt + 1 < ktot) stage(kt+1, p^1);
    if (kt > kmax_w) continue;

    f32x4 st[2][4];
    #pragma unroll
    for (int nt = 0; nt < 4; nt++) {
      int key = nt*16 + c16, x = key & 7;
      short8 a0 = *(const short8*)(&Kt[p][key*64 + ((quad    ) ^ x)*8]);
      short8 a1 = *(const short8*)(&Kt[p][key*64 + ((quad + 4) ^ x)*8]);
      #pragma unroll
      for (int qh = 0; qh < 2; qh++) {
        f32x4 s = f32x4{0.f,0.f,0.f,0.f};
        s = __builtin_amdgcn_mfma_f32_16x16x32_bf16(a0, bq[qh][0], s, 0, 0, 0);
        s = __builtin_amdgcn_mfma_f32_16x16x32_bf16(a1, bq[qh][1], s, 0, 0, 0);
        st[qh][nt] = s;
      }
    }
    if (kt >= 2*qt) {
      const int kb = kt*64;
      #pragma unroll
      for (int qh = 0; qh < 2; qh++) {
        const int qr = q0r + qh*16 + c16;
        #pragma unroll
        for (int nt = 0; nt < 4; nt++) {
          #pragma unroll
          for (int r = 0; r < 4; r++) {
            float e = __builtin_amdgcn_exp2f(st[qh][nt][r]);
            st[qh][nt][r] = (kb + nt*16 + quad*4 + r <= qr) ? e : 0.f;
          }
          lacc[qh] += st[qh][nt];
        }
      }
    } else {
      #pragma unroll
      for (int qh = 0; qh < 2; qh++)
        #pragma unroll
        for (int nt = 0; nt < 4; nt++) {
          #pragma unroll
          for (int r = 0; r < 4; r++) st[qh][nt][r] = __builtin_amdgcn_exp2f(st[qh][nt][r]);
          lacc[qh] += st[qh][nt];
        }
    }
    #pragma unroll
    for (int qh = 0; qh < 2; qh++) {
      const int prow = qh*16 + c16;
      #pragma unroll
      for (int nt = 0; nt < 4; nt++) {
        uint2 pk;
        pk.x = pkbf(st[qh][nt][0], st[qh][nt][1]);
        pk.y = pkbf(st[qh][nt][2], st[qh][nt][3]);
        *(uint2*)(&Ps[wid][prow*68 + nt*16 + quad*4]) = pk;
      }
    }
    short8 bp[2][2];
    #pragma unroll
    for (int qh = 0; qh < 2; qh++) {
      bp[qh][0] = *(const short8*)(&Ps[wid][(qh*16 + c16)*68 +      quad*8]);
      bp[qh][1] = *(const short8*)(&Ps[wid][(qh*16 + c16)*68 + 32 + quad*8]);
    }
    #pragma unroll
    for (int nt = 0; nt < 4; nt++) {
      int dh = nt*16 + c16, x = dh & 7;
      short8 a0 = *(const short8*)(&Vt[p][dh*64 + ((quad    ) ^ x)*8]);
      short8 a1 = *(const short8*)(&Vt[p][dh*64 + ((quad + 4) ^ x)*8]);
      #pragma unroll
      for (int qh = 0; qh < 2; qh++) {
        oacc[qh][nt] = __builtin_amdgcn_mfma_f32_16x16x32_bf16(a0, bp[qh][0], oacc[qh][nt], 0, 0, 0);
        oacc[qh][nt] = __builtin_amdgcn_mfma_f32_16x16x32_bf16(a1, bp[qh][1], oacc[qh][nt], 0, 0, 0);
      }
    }
  }
  #pragma unroll
  for (int qh = 0; qh < 2; qh++) {
    float ls = lacc[qh][0] + lacc[qh][1] + lacc[qh][2] + lacc[qh][3];
    ls += __shfl_xor(ls, 16);
    ls += __shfl_xor(ls, 32);
    const float rl = 1.f / ls;
    #pragma unroll
    for (int nt = 0; nt < 4; nt++) {
      uint2 o;
      o.x = pkbf(oacc[qh][nt][0]*rl, oacc[qh][nt][1]*rl);
      o.y = pkbf(oacc[qh][nt][2]*rl, oacc[qh][nt][3]*rl);
      *(uint2*)(Ow + (size_t)(q0r + qh*16 + c16)*1024 + nt*16 + quad*4) = o;
    }
  }
}

// -------- Gram matrix over repeat map (bf16 Y): per-block partials, no atomics --------
__global__ __launch_bounds__(256) void gram_k(const u16* __restrict__ Y0, const u16* __restrict__ Y1,
                                              const u16* __restrict__ Y2, float* __restrict__ Gpart) {
  float a[6] = {0,0,0,0,0,0};
  const int total8 = CNT/8;   // 524288
  for (int i = blockIdx.x*256 + threadIdx.x; i < total8; i += gridDim.x*256) {
    int d8 = i & 127; int n = (i >> 7) & (N_-1); int b = i >> 18;
    u16x8 y0v = *(const u16x8*)(Y0 + (size_t)i*8);
    u16x8 y1v = *(const u16x8*)(Y1 + (((size_t)(b*1024 + (n>>1))) << 10) + d8*8);
    u16x8 y2v = *(const u16x8*)(Y2 + (((size_t)(b*512  + (n>>2))) << 10) + d8*8);
    #pragma unroll
    for (int t = 0; t < 8; t++) {
      float y0 = bf2f(y0v[t]), y1 = bf2f(y1v[t]), y2 = bf2f(y2v[t]);
      a[0] += y0*y0; a[1] += y0*y1; a[2] += y0*y2;
      a[3] += y1*y1; a[4] += y1*y2; a[5] += y2*y2;
    }
  }
  __shared__ float red[4][6];
  const int lane = threadIdx.x & 63, wid = threadIdx.x >> 6;
  #pragma unroll
  for (int t = 0; t < 6; t++) {
    float v = a[t];
    v += __shfl_xor(v, 1);  v += __shfl_xor(v, 2);  v += __shfl_xor(v, 4);
    v += __shfl_xor(v, 8);  v += __shfl_xor(v, 16); v += __shfl_xor(v, 32);
    a[t] = v;
  }
  if (lane == 0)
    #pragma unroll
    for (int t = 0; t < 6; t++) red[wid][t] = a[t];
  __syncthreads();
  if (threadIdx.x < 6)
    Gpart[(size_t)blockIdx.x*8 + threadIdx.x] =
        red[0][threadIdx.x] + red[1][threadIdx.x] + red[2][threadIdx.x] + red[3][threadIdx.x];
}

// ---- head: reduce 1024 block-partials + Nash + aux + both Sinkhorns (1 block) ----
__global__ __launch_bounds__(256) void head_k(const float* __restrict__ Gpart, float* __restrict__ SC,
                                              const float* __restrict__ agg, const float* __restrict__ mA,
                                              const float* __restrict__ mF, float* __restrict__ aux_out) {
  const int tid = threadIdx.x, lane = tid & 63, wid = tid >> 6;
  float part[6];
  #pragma unroll
  for (int t = 0; t < 6; t++) {
    float v = 0.f;
    #pragma unroll
    for (int j = 0; j < 4; j++) v += Gpart[(size_t)(tid + j*256)*8 + t];
    v += __shfl_xor(v, 1);  v += __shfl_xor(v, 2);  v += __shfl_xor(v, 4);
    v += __shfl_xor(v, 8);  v += __shfl_xor(v, 16); v += __shfl_xor(v, 32);
    part[t] = v;
  }
  __shared__ float red[4][6];
  if (lane == 0)
    #pragma unroll
    for (int t = 0; t < 6; t++) red[wid][t] = part[t];
  __syncthreads();
  if (tid != 0) return;
  float G[6];
  for (int t = 0; t < 6; t++) G[t] = red[0][t] + red[1][t] + red[2][t] + red[3][t];
  const int gi[3][3] = {{0,1,2},{1,3,4},{2,4,5}};
  float a[3] = {agg[0], agg[1], agg[2]};
  float w[3];
  {
    float m = fmaxf(a[0], fmaxf(a[1], a[2])); float s = 0.f;
    for (int l = 0; l < 3; l++) { w[l] = expf(a[l]-m); s += w[l]; }
    for (int l = 0; l < 3; l++) w[l] /= s;
  }
  const float inv = 1.f / (float)CNT;
  for (int it = 0; it < 3; it++) {
    float q = 0.f;
    for (int l = 0; l < 3; l++) for (int m2 = 0; m2 < 3; m2++) q += w[l]*w[m2]*G[gi[l][m2]];
    float z[3];
    for (int l = 0; l < 3; l++) {
      float dot = w[0]*G[gi[l][0]] + w[1]*G[gi[l][1]] + w[2]*G[gi[l][2]];
      z[l] = a[l] - (G[gi[l][l]] - 2.f*dot + q) * inv;
    }
    float m = fmaxf(z[0], fmaxf(z[1], z[2])); float s = 0.f;
    for (int l = 0; l < 3; l++) { w[l] = expf(z[l]-m); s += w[l]; }
    for (int l = 0; l < 3; l++) w[l] /= s;
  }
  SC[6] = w[0]; SC[7] = w[1]; SC[8] = w[2];
  aux_out[0] = w[0]*logf(w[0]*3.f + 1e-9f) + w[1]*logf(w[1]*3.f + 1e-9f) + w[2]*logf(w[2]*3.f + 1e-9f);
  for (int which = 0; which < 2; which++) {
    const float* Lg = which ? mF : mA;
    float M0 = expf(Lg[0]), M1 = expf(Lg[1]), M2 = expf(Lg[2]), M3 = expf(Lg[3]);
    for (int i2 = 0; i2 < 10; i2++) {
      float r0 = M0+M1, r1 = M2+M3; M0 /= r0; M1 /= r0; M2 /= r1; M3 /= r1;
      float c0 = M0+M2, c1 = M1+M3; M0 /= c0; M2 /= c0; M1 /= c1; M3 /= c1;
    }
    SC[9 + which*2] = M0; SC[10 + which*2] = M1;
  }
}

// ---------------- fused mix1 + FFN RMSNorm: one row per block ----------------
__global__ __launch_bounds__(256) void mixrms_k(const float* __restrict__ x, const u16* __restrict__ Y0,
                                                const u16* __restrict__ Y1, const u16* __restrict__ Y2,
                                                const float* __restrict__ SC, const float* __restrict__ w2,
                                                float* __restrict__ x1, u16* __restrict__ xn2) {
  const float w0 = SC[6], w1 = SC[7], ww2 = SC[8], p0 = SC[9], p1 = SC[10];
  const int i = blockIdx.x;
  const int b = i >> 11, n = i & 2047;
  const float* xr = x + (size_t)i * D_;
  const u16* y0 = Y0 + (size_t)i * D_;
  const u16* y1 = Y1 + (size_t)(b*1024 + (n>>1)) * D_;
  const u16* y2 = Y2 + (size_t)(b*512  + (n>>2)) * D_;
  float xv[4], wv[4];
  float ss = 0.f;
  #pragma unroll
  for (int t = 0; t < 4; t++) {
    int c = threadIdx.x + t*256;
    float v = p0*xr[c] + p1*(w0*bf2f(y0[c]) + w1*bf2f(y1[c]) + ww2*bf2f(y2[c]));
    xv[t] = v; wv[t] = w2[c]; ss += v*v;
    x1[(size_t)i*D_ + c] = v;
  }
  #pragma unroll
  for (int o = 1; o < 64; o <<= 1) ss += __shfl_xor(ss, o);
  __shared__ float red[4];
  if ((threadIdx.x & 63) == 0) red[threadIdx.x >> 6] = ss;
  __syncthreads();
  float sc = rsqrtf((red[0]+red[1]+red[2]+red[3]) * (1.f/D_) + 1e-6f);
  #pragma unroll
  for (int t = 0; t < 4; t++) {
    int c = threadIdx.x + t*256;
    xn2[(size_t)i*D_ + c] = f2bf(xv[t]*wv[t]*sc);
  }
}

// ================================ host launcher ================================
extern "C" void kernel_launch(void* const* d_in, const int* in_sizes, int n_in,
                              void* d_out, int out_size, void* d_ws, size_t ws_size,
                              hipStream_t stream) {
  (void)in_sizes; (void)n_in; (void)out_size; (void)ws_size;
  const float* x    = (const float*)d_in[0];
  const float* nw1  = (const float*)d_in[1];
  const float* nw2  = (const float*)d_in[2];
  const float* Wdec = (const float*)d_in[3];
  const float* Wq   = (const float*)d_in[4];
  const float* Wk   = (const float*)d_in[5];
  const float* Wv   = (const float*)d_in[6];
  const float* Wo   = (const float*)d_in[7];
  const float* agg  = (const float*)d_in[8];
  const float* Wg   = (const float*)d_in[9];
  const float* Wu   = (const float*)d_in[10];
  const float* Wdn  = (const float*)d_in[11];
  const float* mA   = (const float*)d_in[12];
  const float* mF   = (const float*)d_in[13];
  float* out = (float*)d_out;

  char* ws = (char*)d_ws;
  size_t off = 0;
  auto take = [&](size_t b) { size_t r = off; off += (b + 255) & ~(size_t)255; return r; };

  u16* A_wp  = (u16*)(ws + take((size_t)9216*1024*2));
  u16* WdecB = (u16*)(ws + take((size_t)3*1024*1024*2));
  u16* Wqkv  = (u16*)(ws + take((size_t)9216*1024*2));
  u16* BTgu  = (u16*)(ws + take((size_t)5632*1024*2));   // gate/up 16-col interleaved
  u16* WdnT  = (u16*)(ws + take((size_t)HIDP*1024*2));
  u16* WoT   = (u16*)(ws + take((size_t)1024*1024*2));
  u16* xn_all = (u16*)(ws + take((size_t)7168*1024*2));
  float* x1  = (float*)(ws + take((size_t)CNT*4));
  float* SCb = (float*)(ws + take(256));
  float* Gpart = (float*)(ws + take((size_t)1024*8*4));  // per-block gram partials
  char*  big = ws + take(88080384);
  // attention phase
  u16*   QKV   = (u16*)big;                              // [7168, 3072] bf16 (V cols unused)
  u16*   VTa   = (u16*)(big + 44040192);                 // per-level [b][1024][Nl]
  u16*   Ob    = (u16*)(big + 58720256);                 // [7168, 1024] bf16
  u16*   YC    = (u16*)(big + 73400320);                 // [7168, 1024] bf16
  // FFN phase alias (attention working set dead by then; YC region untouched)
  u16*   hbuf  = (u16*)big;                              // [4096, 2816] bf16

  u16* xp1 = xn_all + (size_t)4096*1024;
  u16* xp2 = xn_all + (size_t)6144*1024;

  dim3 blk(256);
  const int BIG = 1 << 30;

  // ---- 1: all weight prep + SCb zero + BTgu pad + rmsA4 (norm + both pools) ----
  wprep_k<<<22948, blk, 0, stream>>>(Wdec, Wq, Wk, Wv, Wo, Wg, Wu, Wdn,
                                     A_wp, WdecB, WoT, BTgu, WdnT, SCb,
                                     x, nw1, xn_all, xp1, xp2);
  // ---- 2: fused QKV weights: F_l^T = [Wq|Wk|Wv]_l^T x Wdec_l^T ----
  gemm_t<4,1><<<dim3(8, 72), blk, 0, stream>>>(A_wp, WdecB, Wqkv, nullptr, nullptr, nullptr,
                                               1024, 1024, 24, 48, 1024u*1024u);
  // ---- 3: QKV GEMM (per-level weight select) + fused V transpose epilogue ----
  gemm_t<4,4><<<dim3(24, 56), blk, 0, stream>>>(xn_all, Wqkv, QKV, VTa, nullptr, nullptr,
                                                3072, 1024, 32, 48, 3072u*1024u);
  // ---- 4: flash attention (all levels) ----
  flash_k<<<896, blk, 0, stream>>>(QKV, VTa, Ob);
  // ---- 5: output projection -> YC (bf16) ----
  gemm_t<4,1><<<dim3(8, 56), blk, 0, stream>>>(Ob, WoT, YC, nullptr, nullptr, nullptr,
                                               1024, 1024, BIG, BIG, 0u);
  // ---- 6-7: Gram per-block partials (no atomics), then 1-block head ----
  u16* YC1 = YC + (size_t)4096*1024;
  u16* YC2 = YC + (size_t)6144*1024;
  gram_k<<<1024, blk, 0, stream>>>(YC, YC1, YC2, Gpart);
  head_k<<<1, blk, 0, stream>>>(Gpart, SCb, agg, mA, mF, out + CNT);
  // ---- 8: mix1 + FFN RMSNorm fused ----
  mixrms_k<<<4096, blk, 0, stream>>>(x, YC, YC1, YC2, SCb, nw2, x1, xn_all);
  // ---- 9: gate/up GEMM with fused silu*mul epilogue ----
  gemm_t<4,3><<<dim3(44, 32), blk, 0, stream>>>(xn_all, BTgu, hbuf, nullptr, nullptr, nullptr,
                                                5632, 1024, BIG, BIG, 0u);
  // ---- 10: down GEMM (R3 config: MT=4, 256 blocks), fused final residual mix ----
  gemm_t<4,2><<<dim3(8, 32), blk, 0, stream>>>(hbuf, WdnT, out, nullptr, x1, SCb,
                                               1024, HIDP, BIG, BIG, 0u);
}

// Round 9
// 460.032 us; speedup vs baseline: 1.1651x; 1.0437x over previous
//
#include <hip/hip_runtime.h>
#include <stdint.h>

// MAHA decoder block, MI355X/gfx950. Round 14: grid packing + prep bandwidth —
// down-proj MT=2 (512 tiles, full machine); wqkv MT=3 (768 tiles = 1.5 rounds);
// wprep transposes widened to 64x64 tiles (128B-contiguous bf16 writes, 2.6x
// fewer blocks). GEMM K-loop untouched (R3 structure; 6 schedule nulls = at the
// short-K structural ceiling). Gram de-serialized per R8.
// B=2, N=2048, D=1024, H=16(dh=64), L=3, R=2, HID=2734(->2816), fp32 I/O.

#define B_   2
#define N_   2048
#define D_   1024
#define H_   16
#define DH_  64
#define HID_ 2734
#define HIDP 2816
#define CNT  (B_*N_*D_)   // 4194304
#define LOG2E 1.4426950408889634f

typedef unsigned short u16;
typedef __attribute__((ext_vector_type(8))) short short8;
typedef __attribute__((ext_vector_type(4))) float f32x4;
typedef __attribute__((ext_vector_type(4))) uint16_t u16x4;
typedef __attribute__((ext_vector_type(8))) uint16_t u16x8;

__device__ __forceinline__ u16 f2bf(float f) {
  uint32_t u = __builtin_bit_cast(uint32_t, f);
  u += 0x7fffu + ((u >> 16) & 1u);          // RNE
  return (u16)(u >> 16);
}
__device__ __forceinline__ float bf2f(u16 h) {
  uint32_t u = ((uint32_t)h) << 16;
  return __builtin_bit_cast(float, u);
}
__device__ __forceinline__ uint32_t pkbf(float a, float b) {
  return (uint32_t)f2bf(a) | ((uint32_t)f2bf(b) << 16);
}
__device__ __forceinline__ void gload_lds16(const void* g, void* l) {
  __builtin_amdgcn_global_load_lds(
      (const __attribute__((address_space(1))) uint32_t*)g,
      (__attribute__((address_space(3))) uint32_t*)l, 16, 0, 0);
}

// ============ batched prep: 64x64 weight transposes + Wdec convert + SC zero + rmsA4 ====
// blocks: [0,2304) QKV-w 64x64 transposes | [2304,2560) Wo | [2560,3248) Wg(gate-ilv)
// [3248,3936) Wu(up-ilv) | [3936,4624) Wdn | [4624,7696) Wdec convert (+SC zero)
// [7696,7860) BTgu pad zero | [7860,8884) rmsA4: 4 rows RMSNorm + pool1 + pool2
__global__ __launch_bounds__(256) void wprep_k(const float* __restrict__ Wdec, const float* __restrict__ Wq,
                                               const float* __restrict__ Wk, const float* __restrict__ Wv,
                                               const float* __restrict__ Wo, const float* __restrict__ Wg,
                                               const float* __restrict__ Wu, const float* __restrict__ Wdn,
                                               u16* __restrict__ A_wp, u16* __restrict__ WdecB,
                                               u16* __restrict__ WoT, u16* __restrict__ BTgu,
                                               u16* __restrict__ WdnT, float* __restrict__ SCb,
                                               const float* __restrict__ x, const float* __restrict__ nw1,
                                               u16* __restrict__ xn, u16* __restrict__ xp1,
                                               u16* __restrict__ xp2) {
  const int bid = blockIdx.x;
  const int tid = threadIdx.x;
  if (bid >= 7860) {
    // ---- rmsA4: 4 rows per block, both pool levels in-register ----
    const int j = bid - 7860;
    const float* xr = x + (size_t)(4*j) * D_;
    float a0[4], a1[4], a2[4], a3[4], wv[4];
    float s0=0.f, s1=0.f, s2=0.f, s3=0.f;
    #pragma unroll
    for (int i = 0; i < 4; i++) {
      int c = tid + i*256;
      wv[i] = nw1[c];
      a0[i] = xr[c]; a1[i] = xr[D_+c]; a2[i] = xr[2*D_+c]; a3[i] = xr[3*D_+c];
      s0 += a0[i]*a0[i]; s1 += a1[i]*a1[i]; s2 += a2[i]*a2[i]; s3 += a3[i]*a3[i];
    }
    #pragma unroll
    for (int o = 1; o < 64; o <<= 1) {
      s0 += __shfl_xor(s0, o); s1 += __shfl_xor(s1, o);
      s2 += __shfl_xor(s2, o); s3 += __shfl_xor(s3, o);
    }
    __shared__ float rr[4][4];
    if ((tid & 63) == 0) { int w = tid >> 6; rr[w][0]=s0; rr[w][1]=s1; rr[w][2]=s2; rr[w][3]=s3; }
    __syncthreads();
    float m0v = rr[0][0]+rr[1][0]+rr[2][0]+rr[3][0];
    float m1v = rr[0][1]+rr[1][1]+rr[2][1]+rr[3][1];
    float m2v = rr[0][2]+rr[1][2]+rr[2][2]+rr[3][2];
    float m3v = rr[0][3]+rr[1][3]+rr[2][3]+rr[3][3];
    float c0 = rsqrtf(m0v*(1.f/D_) + 1e-6f), c1 = rsqrtf(m1v*(1.f/D_) + 1e-6f);
    float c2 = rsqrtf(m2v*(1.f/D_) + 1e-6f), c3 = rsqrtf(m3v*(1.f/D_) + 1e-6f);
    #pragma unroll
    for (int i = 0; i < 4; i++) {
      int c = tid + i*256;
      float v0 = a0[i]*wv[i]*c0, v1 = a1[i]*wv[i]*c1;
      float v2 = a2[i]*wv[i]*c2, v3 = a3[i]*wv[i]*c3;
      xn[(size_t)(4*j)*D_ + c]        = f2bf(v0);
      xn[(size_t)(4*j)*D_ + D_ + c]   = f2bf(v1);
      xn[(size_t)(4*j)*D_ + 2*D_ + c] = f2bf(v2);
      xn[(size_t)(4*j)*D_ + 3*D_ + c] = f2bf(v3);
      xp1[(size_t)(2*j)*D_ + c]       = f2bf(0.5f*(v0 + v1));
      xp1[(size_t)(2*j)*D_ + D_ + c]  = f2bf(0.5f*(v2 + v3));
      xp2[(size_t)j*D_ + c]           = f2bf(0.25f*(v0 + v1 + v2 + v3));
    }
    return;
  }
  if (bid >= 7696) {
    int bid0 = bid - 7696;
    int row = (bid0 < 2) ? (5454 + bid0) : (5470 + (bid0 - 2));
    u16x4 zz; zz[0]=0; zz[1]=0; zz[2]=0; zz[3]=0;
    *(u16x4*)(BTgu + (size_t)row*1024 + tid*4) = zz;
    return;
  }
  if (bid >= 4624) {
    if (bid == 4624 && tid < 64) SCb[tid] = 0.f;
    int i = (bid - 4624)*1024 + tid*4;
    float4 v = *(const float4*)(Wdec + i);
    u16x4 o; o[0]=f2bf(v.x); o[1]=f2bf(v.y); o[2]=f2bf(v.z); o[3]=f2bf(v.w);
    *(u16x4*)(WdecB + i) = o;
    return;
  }
  // ---- 64x64 transpose tiles ----
  const float* src; u16* dst; int K, N, KP; float scale; int imode; int bx, by;
  if (bid < 2304) {
    int j = bid >> 8, t = bid & 255; bx = t & 15; by = t >> 4;
    int l = j / 3, which = j - l*3;
    src = which==0 ? Wq + (size_t)l*1048576 : which==1 ? Wk + (size_t)l*1048576 : Wv;
    dst = A_wp + (size_t)(l*3072 + which*1024)*1024;
    K = 1024; N = 1024; KP = 1024; scale = (which==0) ? 0.125f*LOG2E : 1.f; imode = 0;
  } else if (bid < 2560) {
    int t = bid - 2304; bx = t & 15; by = t >> 4;
    src = Wo; dst = WoT; K=1024; N=1024; KP=1024; scale=1.f; imode=0;
  } else if (bid < 3248) {
    int t = bid - 2560; bx = t % 43; by = t / 43;
    src = Wg; dst = BTgu; K=1024; N=HID_; KP=1024; scale=1.f; imode=1;
  } else if (bid < 3936) {
    int t = bid - 3248; bx = t % 43; by = t / 43;
    src = Wu; dst = BTgu; K=1024; N=HID_; KP=1024; scale=1.f; imode=2;
  } else {
    int t = bid - 3936; bx = t & 15; by = t >> 4;
    src = Wdn; dst = WdnT; K=HID_; N=1024; KP=HIDP; scale=1.f; imode=0;
  }
  __shared__ float tt[64][65];
  const int tx = tid & 63, ty = tid >> 6;
  const int nb = bx*64, kb = by*64;
  #pragma unroll
  for (int i = 0; i < 16; i++) {
    int k = kb + ty + i*4, n = nb + tx;
    tt[ty + i*4][tx] = (k < K && n < N) ? src[(size_t)k * N + n] * scale : 0.f;
  }
  __syncthreads();
  #pragma unroll
  for (int i = 0; i < 16; i++) {
    int n = nb + ty + i*4, k = kb + tx;
    if (n < N && k < KP) {
      int r;
      if (imode == 0) r = n;
      else if (imode == 1) r = ((n>>4)<<5) + (n&15);
      else r = ((n>>4)<<5) + 16 + (n&15);
      dst[(size_t)r * KP + k] = f2bf(tt[tx][ty + i*4]);
    }
  }
}

// ---------------- MFMA GEMM, C = A[M,K] * BT[N,K]^T; block = MT*32 x 128, BK=64 ----
// Counted-vmcnt dbuf pipeline (R3 best-measured). MODE 1: bf16 store. MODE 2: fp32
// out = SCp[11]*X1 + SCp[12]*acc. MODE 3: silu(gate)*up epilogue (BTgu interleaved),
// bf16 h store stride HIDP. MODE 4: QKV epilogue — cols<2048 bf16 store; cols>=2048
// V stored transposed into Cv2 (per-level [b][c][n] layout).
template<int MT, int MODE>
__global__ __launch_bounds__(256, 2) void gemm_t(const u16* __restrict__ A, const u16* __restrict__ BT,
                                                 void* __restrict__ Cv, void* __restrict__ Cv2,
                                                 const float* __restrict__ X1,
                                                 const float* __restrict__ SCp,
                                                 int N, int K, int t1, int t2, unsigned int bt_stride) {
  static_assert(MT == 4 || MT == 3 || MT == 2, "vmcnt count assumes MT+4 staging loads");
  __shared__ __align__(16) u16 As[2][MT*32*64];
  __shared__ __align__(16) u16 Bs[2][128*64];
  const int tid = threadIdx.x;
  const int lane = tid & 63, wid = tid >> 6;
  const int quad = lane >> 4, c16 = lane & 15;
  const int y = blockIdx.y;
  const int m0 = y * (MT*32), n0 = blockIdx.x * 128;
  const int wm = wid >> 1, wn = wid & 1;
  const int level = (y >= t2) ? 2 : ((y >= t1) ? 1 : 0);
  BT += (size_t)level * bt_stride;

  f32x4 acc[MT][4];
  #pragma unroll
  for (int i = 0; i < MT; i++)
    #pragma unroll
    for (int j = 0; j < 4; j++) acc[i][j] = f32x4{0.f,0.f,0.f,0.f};

  const int srow = lane >> 3;
  const int schunk = lane & 7;
  auto stage = [&](int k0, int p) {
    #pragma unroll
    for (int t = 0; t < MT; t++) {
      int idx = wid*MT + t;
      int row = idx*8 + srow;
      int g = (schunk ^ (row & 7)) * 8;
      gload_lds16(A + (size_t)(m0+row)*K + k0 + g, &As[p][idx*512]);
    }
    #pragma unroll
    for (int t = 0; t < 4; t++) {
      int idx = wid*4 + t;
      int row = idx*8 + srow;
      int g = (schunk ^ (row & 7)) * 8;
      gload_lds16(BT + (size_t)(n0+row)*K + k0 + g, &Bs[p][idx*512]);
    }
  };

  const int nk = K >> 6;
  stage(0, 0);
  for (int ki = 0; ki < nk; ki++) {
    const int p = ki & 1;
    if (ki + 1 < nk) {
      stage((ki + 1) << 6, p ^ 1);
      if constexpr (MT == 4)      asm volatile("s_waitcnt vmcnt(8)" ::: "memory");
      else if constexpr (MT == 3) asm volatile("s_waitcnt vmcnt(7)" ::: "memory");
      else                        asm volatile("s_waitcnt vmcnt(6)" ::: "memory");
    } else {
      asm volatile("s_waitcnt vmcnt(0)" ::: "memory");
    }
    __builtin_amdgcn_s_barrier();
    __builtin_amdgcn_sched_barrier(0);
    __builtin_amdgcn_s_setprio(1);
    #pragma unroll
    for (int kh = 0; kh < 2; kh++) {
      short8 af[MT], bfr[4];
      #pragma unroll
      for (int mt = 0; mt < MT; mt++) {
        int ar = wm*(MT*16) + mt*16 + c16;
        int ck = (kh*4 + quad) ^ (ar & 7);
        af[mt] = *(const short8*)(&As[p][ar*64 + ck*8]);
      }
      #pragma unroll
      for (int nt = 0; nt < 4; nt++) {
        int br = wn*64 + nt*16 + c16;
        int ck = (kh*4 + quad) ^ (br & 7);
        bfr[nt] = *(const short8*)(&Bs[p][br*64 + ck*8]);
      }
      #pragma unroll
      for (int mt = 0; mt < MT; mt++)
        #pragma unroll
        for (int nt = 0; nt < 4; nt++)
          acc[mt][nt] = __builtin_amdgcn_mfma_f32_16x16x32_bf16(af[mt], bfr[nt], acc[mt][nt], 0, 0, 0);
    }
    __builtin_amdgcn_s_setprio(0);
    __builtin_amdgcn_sched_barrier(0);
    __builtin_amdgcn_s_barrier();
  }
  if (MODE == 1) {
    u16* C = (u16*)Cv;
    #pragma unroll
    for (int mt = 0; mt < MT; mt++)
      #pragma unroll
      for (int nt = 0; nt < 4; nt++)
        #pragma unroll
        for (int r = 0; r < 4; r++) {
          int row = m0 + wm*(MT*16) + mt*16 + quad*4 + r;
          int col = n0 + wn*64 + nt*16 + c16;
          C[(size_t)row * N + col] = f2bf(acc[mt][nt][r]);
        }
  } else if (MODE == 2) {
    float* C = (float*)Cv;
    const float q0 = SCp[11], q1 = SCp[12];
    #pragma unroll
    for (int mt = 0; mt < MT; mt++)
      #pragma unroll
      for (int nt = 0; nt < 4; nt++)
        #pragma unroll
        for (int r = 0; r < 4; r++) {
          int row = m0 + wm*(MT*16) + mt*16 + quad*4 + r;
          int col = n0 + wn*64 + nt*16 + c16;
          size_t o = (size_t)row * N + col;
          C[o] = q0 * X1[o] + q1 * acc[mt][nt][r];
        }
  } else if (MODE == 3) {
    u16* Hc = (u16*)Cv;
    const int hbase = (n0 >> 1) + wn*32;
    #pragma unroll
    for (int mt = 0; mt < MT; mt++)
      #pragma unroll
      for (int r = 0; r < 4; r++) {
        int row = m0 + wm*(MT*16) + mt*16 + quad*4 + r;
        #pragma unroll
        for (int pr = 0; pr < 2; pr++) {
          float g = acc[mt][2*pr][r], u = acc[mt][2*pr+1][r];
          float h = g / (1.f + __expf(-g)) * u;
          Hc[(size_t)row * HIDP + hbase + pr*16 + c16] = f2bf(h);
        }
      }
  } else {  // MODE 4
    if (n0 < 2048) {
      u16* C = (u16*)Cv;
      #pragma unroll
      for (int mt = 0; mt < MT; mt++)
        #pragma unroll
        for (int nt = 0; nt < 4; nt++)
          #pragma unroll
          for (int r = 0; r < 4; r++) {
            int row = m0 + wm*(MT*16) + mt*16 + quad*4 + r;
            int col = n0 + wn*64 + nt*16 + c16;
            C[(size_t)row * N + col] = f2bf(acc[mt][nt][r]);
          }
    } else {
      const int Nl = 2048 >> level;
      const int lvbase = (level==0) ? 0 : (level==1) ? 4096 : 6144;
      const size_t vtoff = (level==0) ? 0 : (level==1) ? 4194304 : 6291456;
      u16* VT = (u16*)Cv2 + vtoff;
      #pragma unroll
      for (int mt = 0; mt < MT; mt++) {
        int rowg = m0 + wm*(MT*16) + mt*16 + quad*4;   // r=0 row; +3 stays in-row-group
        int nloc = rowg - lvbase;
        int b = nloc / Nl;              // Nl is power of two
        int n = nloc - b*Nl;
        #pragma unroll
        for (int nt = 0; nt < 4; nt++) {
          int c = n0 - 2048 + wn*64 + nt*16 + c16;
          u16x4 o;
          o[0]=f2bf(acc[mt][nt][0]); o[1]=f2bf(acc[mt][nt][1]);
          o[2]=f2bf(acc[mt][nt][2]); o[3]=f2bf(acc[mt][nt][3]);
          *(u16x4*)(VT + ((size_t)(b*1024 + c))*Nl + n) = o;
        }
      }
    }
  }
}

// ---------------- MFMA flash attention, all levels merged, no-max online softmax ----
__global__ __launch_bounds__(256) void flash_k(const u16* __restrict__ QKVg,
                                               const u16* __restrict__ VTg,
                                               u16* __restrict__ Og) {
  __shared__ __align__(16) u16 Kt[2][64*64];
  __shared__ __align__(16) u16 Vt[2][64*64];
  __shared__ __align__(16) u16 Ps[4][32*68];
  const int tid = threadIdx.x, lane = tid & 63, wid = tid >> 6;
  const int quad = lane >> 4, c16 = lane & 15;
  const int id = blockIdx.x;
  int qt, bh, Nl, rowbase; size_t vtoff;
  if (id < 512)      { qt = 15 - (id >> 5);            bh = id & 31;  Nl = 2048; rowbase = 0;    vtoff = 0; }
  else if (id < 768) { int t2 = id - 512; qt = 7 - (t2 >> 5); bh = t2 & 31; Nl = 1024; rowbase = 4096; vtoff = 4194304; }
  else               { int t2 = id - 768; qt = 3 - (t2 >> 5); bh = t2 & 31; Nl = 512;  rowbase = 6144; vtoff = 6291456; }
  const int b = bh >> 4, h = bh & 15;
  const u16* QK = QKVg + ((size_t)(rowbase + b*Nl)) * 3072 + h*64;
  u16* Ow = Og + ((size_t)(rowbase + b*Nl)) * 1024 + h*64;
  const u16* VT = VTg + vtoff + ((size_t)b*1024 + h*64) * (size_t)Nl;

  const int q0r = qt*128 + wid*32;
  short8 bq[2][2];
  #pragma unroll
  for (int qh = 0; qh < 2; qh++) {
    const u16* qp = QK + (size_t)(q0r + qh*16 + c16)*3072 + quad*8;
    bq[qh][0] = *(const short8*)qp;
    bq[qh][1] = *(const short8*)(qp + 32);
  }
  const int si0 = wid*2, si1 = si0 + 1;
  const int sr0 = si0*8 + (lane>>3), sr1 = si1*8 + (lane>>3);
  const int sg  = ((lane&7) ^ (lane>>3)) * 8;
  const u16* Ks0 = QK + 1024 + (size_t)sr0*3072 + sg;
  const u16* Ks1 = QK + 1024 + (size_t)sr1*3072 + sg;
  const u16* Vs0 = VT + (size_t)sr0*Nl + sg;
  const u16* Vs1 = VT + (size_t)sr1*Nl + sg;

  f32x4 oacc[2][4];
  f32x4 lacc[2];
  #pragma unroll
  for (int qh = 0; qh < 2; qh++) {
    lacc[qh] = f32x4{0.f,0.f,0.f,0.f};
    #pragma unroll
    for (int nt = 0; nt < 4; nt++) oacc[qh][nt] = f32x4{0.f,0.f,0.f,0.f};
  }

  auto stage = [&](int kt, int p) {
    const size_t ko = (size_t)kt * 64;
    gload_lds16(Ks0 + ko*3072, &Kt[p][si0*512]);
    gload_lds16(Ks1 + ko*3072, &Kt[p][si1*512]);
    gload_lds16(Vs0 + ko,      &Vt[p][si0*512]);
    gload_lds16(Vs1 + ko,      &Vt[p][si1*512]);
  };
  const int kmax_w = 2*qt + (wid >> 1);
  const int ktot   = 2*qt + 2;
  stage(0, 0);

  for (int kt = 0; kt < ktot; kt++) {
    const int p = kt & 1;
    __syncthreads();
    if (kt + 1 < ktot) stage(kt+1, p^1);
    if (kt > kmax_w) continue;

    f32x4 st[2][4];
    #pragma unroll
    for (int nt = 0; nt < 4; nt++) {
      int key = nt*16 + c16, x = key & 7;
      short8 a0 = *(const short8*)(&Kt[p][key*64 + ((quad    ) ^ x)*8]);
      short8 a1 = *(const short8*)(&Kt[p][key*64 + ((quad + 4) ^ x)*8]);
      #pragma unroll
      for (int qh = 0; qh < 2; qh++) {
        f32x4 s = f32x4{0.f,0.f,0.f,0.f};
        s = __builtin_amdgcn_mfma_f32_16x16x32_bf16(a0, bq[qh][0], s, 0, 0, 0);
        s = __builtin_amdgcn_mfma_f32_16x16x32_bf16(a1, bq[qh][1], s, 0, 0, 0);
        st[qh][nt] = s;
      }
    }
    if (kt >= 2*qt) {
      const int kb = kt*64;
      #pragma unroll
      for (int qh = 0; qh < 2; qh++) {
        const int qr = q0r + qh*16 + c16;
        #pragma unroll
        for (int nt = 0; nt < 4; nt++) {
          #pragma unroll
          for (int r = 0; r < 4; r++) {
            float e = __builtin_amdgcn_exp2f(st[qh][nt][r]);
            st[qh][nt][r] = (kb + nt*16 + quad*4 + r <= qr) ? e : 0.f;
          }
          lacc[qh] += st[qh][nt];
        }
      }
    } else {
      #pragma unroll
      for (int qh = 0; qh < 2; qh++)
        #pragma unroll
        for (int nt = 0; nt < 4; nt++) {
          #pragma unroll
          for (int r = 0; r < 4; r++) st[qh][nt][r] = __builtin_amdgcn_exp2f(st[qh][nt][r]);
          lacc[qh] += st[qh][nt];
        }
    }
    #pragma unroll
    for (int qh = 0; qh < 2; qh++) {
      const int prow = qh*16 + c16;
      #pragma unroll
      for (int nt = 0; nt < 4; nt++) {
        uint2 pk;
        pk.x = pkbf(st[qh][nt][0], st[qh][nt][1]);
        pk.y = pkbf(st[qh][nt][2], st[qh][nt][3]);
        *(uint2*)(&Ps[wid][prow*68 + nt*16 + quad*4]) = pk;
      }
    }
    short8 bp[2][2];
    #pragma unroll
    for (int qh = 0; qh < 2; qh++) {
      bp[qh][0] = *(const short8*)(&Ps[wid][(qh*16 + c16)*68 +      quad*8]);
      bp[qh][1] = *(const short8*)(&Ps[wid][(qh*16 + c16)*68 + 32 + quad*8]);
    }
    #pragma unroll
    for (int nt = 0; nt < 4; nt++) {
      int dh = nt*16 + c16, x = dh & 7;
      short8 a0 = *(const short8*)(&Vt[p][dh*64 + ((quad    ) ^ x)*8]);
      short8 a1 = *(const short8*)(&Vt[p][dh*64 + ((quad + 4) ^ x)*8]);
      #pragma unroll
      for (int qh = 0; qh < 2; qh++) {
        oacc[qh][nt] = __builtin_amdgcn_mfma_f32_16x16x32_bf16(a0, bp[qh][0], oacc[qh][nt], 0, 0, 0);
        oacc[qh][nt] = __builtin_amdgcn_mfma_f32_16x16x32_bf16(a1, bp[qh][1], oacc[qh][nt], 0, 0, 0);
      }
    }
  }
  #pragma unroll
  for (int qh = 0; qh < 2; qh++) {
    float ls = lacc[qh][0] + lacc[qh][1] + lacc[qh][2] + lacc[qh][3];
    ls += __shfl_xor(ls, 16);
    ls += __shfl_xor(ls, 32);
    const float rl = 1.f / ls;
    #pragma unroll
    for (int nt = 0; nt < 4; nt++) {
      uint2 o;
      o.x = pkbf(oacc[qh][nt][0]*rl, oacc[qh][nt][1]*rl);
      o.y = pkbf(oacc[qh][nt][2]*rl, oacc[qh][nt][3]*rl);
      *(uint2*)(Ow + (size_t)(q0r + qh*16 + c16)*1024 + nt*16 + quad*4) = o;
    }
  }
}

// -------- Gram matrix over repeat map (bf16 Y): per-block partials, no atomics --------
__global__ __launch_bounds__(256) void gram_k(const u16* __restrict__ Y0, const u16* __restrict__ Y1,
                                              const u16* __restrict__ Y2, float* __restrict__ Gpart) {
  float a[6] = {0,0,0,0,0,0};
  const int total8 = CNT/8;   // 524288
  for (int i = blockIdx.x*256 + threadIdx.x; i < total8; i += gridDim.x*256) {
    int d8 = i & 127; int n = (i >> 7) & (N_-1); int b = i >> 18;
    u16x8 y0v = *(const u16x8*)(Y0 + (size_t)i*8);
    u16x8 y1v = *(const u16x8*)(Y1 + (((size_t)(b*1024 + (n>>1))) << 10) + d8*8);
    u16x8 y2v = *(const u16x8*)(Y2 + (((size_t)(b*512  + (n>>2))) << 10) + d8*8);
    #pragma unroll
    for (int t = 0; t < 8; t++) {
      float y0 = bf2f(y0v[t]), y1 = bf2f(y1v[t]), y2 = bf2f(y2v[t]);
      a[0] += y0*y0; a[1] += y0*y1; a[2] += y0*y2;
      a[3] += y1*y1; a[4] += y1*y2; a[5] += y2*y2;
    }
  }
  __shared__ float red[4][6];
  const int lane = threadIdx.x & 63, wid = threadIdx.x >> 6;
  #pragma unroll
  for (int t = 0; t < 6; t++) {
    float v = a[t];
    v += __shfl_xor(v, 1);  v += __shfl_xor(v, 2);  v += __shfl_xor(v, 4);
    v += __shfl_xor(v, 8);  v += __shfl_xor(v, 16); v += __shfl_xor(v, 32);
    a[t] = v;
  }
  if (lane == 0)
    #pragma unroll
    for (int t = 0; t < 6; t++) red[wid][t] = a[t];
  __syncthreads();
  if (threadIdx.x < 6)
    Gpart[(size_t)blockIdx.x*8 + threadIdx.x] =
        red[0][threadIdx.x] + red[1][threadIdx.x] + red[2][threadIdx.x] + red[3][threadIdx.x];
}

// ---- head: reduce 1024 block-partials + Nash + aux + both Sinkhorns (1 block) ----
__global__ __launch_bounds__(256) void head_k(const float* __restrict__ Gpart, float* __restrict__ SC,
                                              const float* __restrict__ agg, const float* __restrict__ mA,
                                              const float* __restrict__ mF, float* __restrict__ aux_out) {
  const int tid = threadIdx.x, lane = tid & 63, wid = tid >> 6;
  float part[6];
  #pragma unroll
  for (int t = 0; t < 6; t++) {
    float v = 0.f;
    #pragma unroll
    for (int j = 0; j < 4; j++) v += Gpart[(size_t)(tid + j*256)*8 + t];
    v += __shfl_xor(v, 1);  v += __shfl_xor(v, 2);  v += __shfl_xor(v, 4);
    v += __shfl_xor(v, 8);  v += __shfl_xor(v, 16); v += __shfl_xor(v, 32);
    part[t] = v;
  }
  __shared__ float red[4][6];
  if (lane == 0)
    #pragma unroll
    for (int t = 0; t < 6; t++) red[wid][t] = part[t];
  __syncthreads();
  if (tid != 0) return;
  float G[6];
  for (int t = 0; t < 6; t++) G[t] = red[0][t] + red[1][t] + red[2][t] + red[3][t];
  const int gi[3][3] = {{0,1,2},{1,3,4},{2,4,5}};
  float a[3] = {agg[0], agg[1], agg[2]};
  float w[3];
  {
    float m = fmaxf(a[0], fmaxf(a[1], a[2])); float s = 0.f;
    for (int l = 0; l < 3; l++) { w[l] = expf(a[l]-m); s += w[l]; }
    for (int l = 0; l < 3; l++) w[l] /= s;
  }
  const float inv = 1.f / (float)CNT;
  for (int it = 0; it < 3; it++) {
    float q = 0.f;
    for (int l = 0; l < 3; l++) for (int m2 = 0; m2 < 3; m2++) q += w[l]*w[m2]*G[gi[l][m2]];
    float z[3];
    for (int l = 0; l < 3; l++) {
      float dot = w[0]*G[gi[l][0]] + w[1]*G[gi[l][1]] + w[2]*G[gi[l][2]];
      z[l] = a[l] - (G[gi[l][l]] - 2.f*dot + q) * inv;
    }
    float m = fmaxf(z[0], fmaxf(z[1], z[2])); float s = 0.f;
    for (int l = 0; l < 3; l++) { w[l] = expf(z[l]-m); s += w[l]; }
    for (int l = 0; l < 3; l++) w[l] /= s;
  }
  SC[6] = w[0]; SC[7] = w[1]; SC[8] = w[2];
  aux_out[0] = w[0]*logf(w[0]*3.f + 1e-9f) + w[1]*logf(w[1]*3.f + 1e-9f) + w[2]*logf(w[2]*3.f + 1e-9f);
  for (int which = 0; which < 2; which++) {
    const float* Lg = which ? mF : mA;
    float M0 = expf(Lg[0]), M1 = expf(Lg[1]), M2 = expf(Lg[2]), M3 = expf(Lg[3]);
    for (int i2 = 0; i2 < 10; i2++) {
      float r0 = M0+M1, r1 = M2+M3; M0 /= r0; M1 /= r0; M2 /= r1; M3 /= r1;
      float c0 = M0+M2, c1 = M1+M3; M0 /= c0; M2 /= c0; M1 /= c1; M3 /= c1;
    }
    SC[9 + which*2] = M0; SC[10 + which*2] = M1;
  }
}

// ---------------- fused mix1 + FFN RMSNorm: one row per block ----------------
__global__ __launch_bounds__(256) void mixrms_k(const float* __restrict__ x, const u16* __restrict__ Y0,
                                                const u16* __restrict__ Y1, const u16* __restrict__ Y2,
                                                const float* __restrict__ SC, const float* __restrict__ w2,
                                                float* __restrict__ x1, u16* __restrict__ xn2) {
  const float w0 = SC[6], w1 = SC[7], ww2 = SC[8], p0 = SC[9], p1 = SC[10];
  const int i = blockIdx.x;
  const int b = i >> 11, n = i & 2047;
  const float* xr = x + (size_t)i * D_;
  const u16* y0 = Y0 + (size_t)i * D_;
  const u16* y1 = Y1 + (size_t)(b*1024 + (n>>1)) * D_;
  const u16* y2 = Y2 + (size_t)(b*512  + (n>>2)) * D_;
  float xv[4], wv[4];
  float ss = 0.f;
  #pragma unroll
  for (int t = 0; t < 4; t++) {
    int c = threadIdx.x + t*256;
    float v = p0*xr[c] + p1*(w0*bf2f(y0[c]) + w1*bf2f(y1[c]) + ww2*bf2f(y2[c]));
    xv[t] = v; wv[t] = w2[c]; ss += v*v;
    x1[(size_t)i*D_ + c] = v;
  }
  #pragma unroll
  for (int o = 1; o < 64; o <<= 1) ss += __shfl_xor(ss, o);
  __shared__ float red[4];
  if ((threadIdx.x & 63) == 0) red[threadIdx.x >> 6] = ss;
  __syncthreads();
  float sc = rsqrtf((red[0]+red[1]+red[2]+red[3]) * (1.f/D_) + 1e-6f);
  #pragma unroll
  for (int t = 0; t < 4; t++) {
    int c = threadIdx.x + t*256;
    xn2[(size_t)i*D_ + c] = f2bf(xv[t]*wv[t]*sc);
  }
}

// ================================ host launcher ================================
extern "C" void kernel_launch(void* const* d_in, const int* in_sizes, int n_in,
                              void* d_out, int out_size, void* d_ws, size_t ws_size,
                              hipStream_t stream) {
  (void)in_sizes; (void)n_in; (void)out_size; (void)ws_size;
  const float* x    = (const float*)d_in[0];
  const float* nw1  = (const float*)d_in[1];
  const float* nw2  = (const float*)d_in[2];
  const float* Wdec = (const float*)d_in[3];
  const float* Wq   = (const float*)d_in[4];
  const float* Wk   = (const float*)d_in[5];
  const float* Wv   = (const float*)d_in[6];
  const float* Wo   = (const float*)d_in[7];
  const float* agg  = (const float*)d_in[8];
  const float* Wg   = (const float*)d_in[9];
  const float* Wu   = (const float*)d_in[10];
  const float* Wdn  = (const float*)d_in[11];
  const float* mA   = (const float*)d_in[12];
  const float* mF   = (const float*)d_in[13];
  float* out = (float*)d_out;

  char* ws = (char*)d_ws;
  size_t off = 0;
  auto take = [&](size_t b) { size_t r = off; off += (b + 255) & ~(size_t)255; return r; };

  u16* A_wp  = (u16*)(ws + take((size_t)9216*1024*2));
  u16* WdecB = (u16*)(ws + take((size_t)3*1024*1024*2));
  u16* Wqkv  = (u16*)(ws + take((size_t)9216*1024*2));
  u16* BTgu  = (u16*)(ws + take((size_t)5632*1024*2));   // gate/up 16-col interleaved
  u16* WdnT  = (u16*)(ws + take((size_t)HIDP*1024*2));
  u16* WoT   = (u16*)(ws + take((size_t)1024*1024*2));
  u16* xn_all = (u16*)(ws + take((size_t)7168*1024*2));
  float* x1  = (float*)(ws + take((size_t)CNT*4));
  float* SCb = (float*)(ws + take(256));
  float* Gpart = (float*)(ws + take((size_t)1024*8*4));  // per-block gram partials
  char*  big = ws + take(88080384);
  // attention phase
  u16*   QKV   = (u16*)big;                              // [7168, 3072] bf16 (V cols unused)
  u16*   VTa   = (u16*)(big + 44040192);                 // per-level [b][1024][Nl]
  u16*   Ob    = (u16*)(big + 58720256);                 // [7168, 1024] bf16
  u16*   YC    = (u16*)(big + 73400320);                 // [7168, 1024] bf16
  // FFN phase alias (attention working set dead by then; YC region untouched)
  u16*   hbuf  = (u16*)big;                              // [4096, 2816] bf16

  u16* xp1 = xn_all + (size_t)4096*1024;
  u16* xp2 = xn_all + (size_t)6144*1024;

  dim3 blk(256);
  const int BIG = 1 << 30;

  // ---- 1: all weight prep (64x64 tiles) + SCb zero + BTgu pad + rmsA4 ----
  wprep_k<<<8884, blk, 0, stream>>>(Wdec, Wq, Wk, Wv, Wo, Wg, Wu, Wdn,
                                    A_wp, WdecB, WoT, BTgu, WdnT, SCb,
                                    x, nw1, xn_all, xp1, xp2);
  // ---- 2: fused QKV weights (MT=3: 96-row tiles, 768 = 1.5 rounds) ----
  gemm_t<3,1><<<dim3(8, 96), blk, 0, stream>>>(A_wp, WdecB, Wqkv, nullptr, nullptr, nullptr,
                                               1024, 1024, 32, 64, 1024u*1024u);
  // ---- 3: QKV GEMM (per-level weight select) + fused V transpose epilogue ----
  gemm_t<4,4><<<dim3(24, 56), blk, 0, stream>>>(xn_all, Wqkv, QKV, VTa, nullptr, nullptr,
                                                3072, 1024, 32, 48, 3072u*1024u);
  // ---- 4: flash attention (all levels) ----
  flash_k<<<896, blk, 0, stream>>>(QKV, VTa, Ob);
  // ---- 5: output projection -> YC (bf16) ----
  gemm_t<4,1><<<dim3(8, 56), blk, 0, stream>>>(Ob, WoT, YC, nullptr, nullptr, nullptr,
                                               1024, 1024, BIG, BIG, 0u);
  // ---- 6-7: Gram per-block partials (no atomics), then 1-block head ----
  u16* YC1 = YC + (size_t)4096*1024;
  u16* YC2 = YC + (size_t)6144*1024;
  gram_k<<<1024, blk, 0, stream>>>(YC, YC1, YC2, Gpart);
  head_k<<<1, blk, 0, stream>>>(Gpart, SCb, agg, mA, mF, out + CNT);
  // ---- 8: mix1 + FFN RMSNorm fused ----
  mixrms_k<<<4096, blk, 0, stream>>>(x, YC, YC1, YC2, SCb, nw2, x1, xn_all);
  // ---- 9: gate/up GEMM with fused silu*mul epilogue ----
  gemm_t<4,3><<<dim3(44, 32), blk, 0, stream>>>(xn_all, BTgu, hbuf, nullptr, nullptr, nullptr,
                                                5632, 1024, BIG, BIG, 0u);
  // ---- 10: down GEMM, MT=2 (512 tiles -> full machine), fused final residual mix ----
  gemm_t<2,2><<<dim3(8, 64), blk, 0, stream>>>(hbuf, WdnT, out, nullptr, x1, SCb,
                                               1024, HIDP, BIG, BIG, 0u);
}